// Round 8
// baseline (431.319 us; speedup 1.0000x reference)
//
#include <hip/hip_runtime.h>
#include <hip/hip_bf16.h>
#include <cstdint>

typedef unsigned short u16;
typedef unsigned int u32;
typedef __attribute__((ext_vector_type(8))) short short8;   // 8 bf16 MFMA A/B frag
typedef __attribute__((ext_vector_type(4))) float f32x4;    // MFMA C/D frag
typedef __attribute__((ext_vector_type(4))) unsigned int u32x4;
typedef __attribute__((ext_vector_type(4))) unsigned short u16x4;

#define REV 15.91549431f   // 100/(2*pi)
#define NBLK 768u          // 3 blocks/CU x 256 CUs — exact co-residency

// ---------- helpers ----------
__device__ __forceinline__ u16 f2b(float x) { return __builtin_bit_cast(u16, (__bf16)x); }
__device__ __forceinline__ u16 f2h(float x) { return __builtin_bit_cast(u16, (_Float16)x); }
__device__ __forceinline__ float c_dim_f(int f) {
    const float c[8] = {1.0f, 0.42169650f, 0.17782794f, 0.074989421f,
                        0.031622777f, 0.013335214f, 0.0056234132f, 0.0023713737f};
    return c[f];
}
__device__ __forceinline__ void gload_lds16(const void* g, void* l) {
    __builtin_amdgcn_global_load_lds((const __attribute__((address_space(1))) u32*)g,
                                     (__attribute__((address_space(3))) u32*)l, 16, 0, 0);
}

union SharedMem {
    char embs[256 * 128];                                   // geom: [256 pairs][64 bf16]
    struct { u16 As[64 * 32]; u16 Bs[64 * 32]; } g;         // GEMM staging
    struct { u16 Pl[4][16 * 68]; float Mrg[3][64][25]; } a; // attn
};

// one-shot grid barrier: arrive, spin to NBLK. Agent-scope atomics + fences
// (threadfence emits the cross-XCD L2 wb/inv). Requires all blocks co-resident.
__device__ __forceinline__ void gsync(u32* c) {
    __syncthreads();
    if (threadIdx.x == 0) {
        __threadfence();   // release: producer writes -> coherent point
        __hip_atomic_fetch_add(c, 1u, __ATOMIC_ACQ_REL, __HIP_MEMORY_SCOPE_AGENT);
        while (__hip_atomic_load(c, __ATOMIC_ACQUIRE, __HIP_MEMORY_SCOPE_AGENT) < NBLK)
            __builtin_amdgcn_s_sleep(2);
        __threadfence();   // acquire: invalidate stale L2
    }
    __syncthreads();
}

__global__ __launch_bounds__(256, 3) void fused_k(
        const float* __restrict__ inq, const float* __restrict__ ink,
        const float* __restrict__ inv, const float* __restrict__ box,
        const float* __restrict__ Wq, const float* __restrict__ bq,
        const float* __restrict__ Wk, const float* __restrict__ bk,
        const float* __restrict__ Wv, const float* __restrict__ bv,
        const float* __restrict__ Wo, const float* __restrict__ bo,
        const float* __restrict__ WG, const float* __restrict__ bG,
        u16* __restrict__ Xall, u16* __restrict__ Wall,
        u16* __restrict__ Qb, u16* __restrict__ Kb, u16* __restrict__ VT,
        u16* __restrict__ ATT, u16* __restrict__ Wp,
        float* __restrict__ outF, u32* __restrict__ bars) {
    __shared__ SharedMem sh;
    const int t = threadIdx.x;
    const int wave = t >> 6, lane = t & 63;
    const int bid = blockIdx.x;

    // ===== phase 0a: f32 -> bf16 conversion (grid-stride) =====
    {
        const float* xs[3] = {inq, ink, inv};
        const float* wsrc[4] = {Wq, Wk, Wv, Wo};
        for (u32 idx = (u32)bid * 256u + (u32)t; idx < 1048576u; idx += 196608u) {
            const float* s; u16* dst; u32 off;
            if (idx < 786432u) {                       // X: 3 x 262144 float4
                u32 z = idx >> 18; off = (idx & 262143u) << 2;
                s = xs[z]; dst = Xall + ((size_t)z << 20) + off;
            } else {                                   // W: 4 x 65536 float4
                u32 w = idx - 786432u; u32 z = w >> 16; off = (w & 65535u) << 2;
                s = wsrc[z]; dst = Wall + ((size_t)z << 18) + off;
            }
            float4 v = *(const float4*)&s[off];
            u16x4 o = { f2b(v.x), f2b(v.y), f2b(v.z), f2b(v.w) };
            *(u16x4*)dst = o;
        }
    }

    // ===== phase 0b: geometry weights w = 1024*max(relu(emb@WG+bG),1e-6) f16 =====
    {
        const int hh = lane & 15;
        const int ko = (lane >> 4) << 3;
        short8 bf0 = {0,0,0,0,0,0,0,0}, bf1 = {0,0,0,0,0,0,0,0};
        float bGh = 0.0f;
        if (hh < 8) {
            const float* wrow = WG + hh * 64;
#pragma unroll
            for (int e = 0; e < 8; e++) {
                bf0[e] = (short)f2b(wrow[ko + e]);
                bf1[e] = (short)f2b(wrow[32 + ko + e]);
            }
            bGh = bG[hh];
        }
        for (u32 u = (u32)bid; u < 4096u; u += NBLK) {
            const int b = (int)(u >> 10);
            const int ii = (int)((u & 1023u) >> 1);
            const int jt = (int)(u & 1u);
            const int j = (jt << 8) + t;
            const int swz = (t & 7) << 4;

            float4 bi = *(const float4*)&box[(size_t)(((b << 9) + ii) << 2)];
            float4 bj = *(const float4*)&box[(size_t)(((b << 9) + j) << 2)];
            float cxi = (bi.x + bi.z) * 0.5f, cyi = (bi.y + bi.w) * 0.5f;
            float wdi = bi.z - bi.x + 1.0f,  hgi = bi.w - bi.y + 1.0f;
            float cxj = (bj.x + bj.z) * 0.5f, cyj = (bj.y + bj.w) * 0.5f;
            float wdj = bj.z - bj.x + 1.0f,  hgj = bj.w - bj.y + 1.0f;

            float pos[4];
            pos[0] = __logf(fmaxf(fabsf((cxi - cxj) / wdi), 1e-3f));
            pos[1] = __logf(fmaxf(fabsf((cyi - cyj) / hgi), 1e-3f));
            pos[2] = __logf(wdi) - __logf(wdj);
            pos[3] = __logf(hgi) - __logf(hgj);

#pragma unroll
            for (int p = 0; p < 4; p++) {
                float rev = pos[p] * REV;
                u32x4 sp, cp;
#pragma unroll
                for (int f = 0; f < 4; f++) {
                    float a0 = rev * c_dim_f(2 * f), a1 = rev * c_dim_f(2 * f + 1);
                    sp[f] = (u32)f2b(__builtin_amdgcn_sinf(a0)) | ((u32)f2b(__builtin_amdgcn_sinf(a1)) << 16);
                    cp[f] = (u32)f2b(__builtin_amdgcn_cosf(a0)) | ((u32)f2b(__builtin_amdgcn_cosf(a1)) << 16);
                }
                *(u32x4*)(sh.embs + (((t << 7) + (p << 4)) ^ swz)) = sp;
                *(u32x4*)(sh.embs + (((t << 7) + 64 + (p << 4)) ^ swz)) = cp;
            }
            __syncthreads();

#pragma unroll
            for (int tt = 0; tt < 4; tt++) {
                int mt = (wave << 2) + tt;
                int row = (mt << 4) + hh;
                int rswz = (row & 7) << 4;
                short8 a0v = *(const short8*)(sh.embs + (((row << 7) + (ko << 1)) ^ rswz));
                short8 a1v = *(const short8*)(sh.embs + (((row << 7) + 64 + (ko << 1)) ^ rswz));
                f32x4 acc = {0.f, 0.f, 0.f, 0.f};
                acc = __builtin_amdgcn_mfma_f32_16x16x32_bf16(a0v, bf0, acc, 0, 0, 0);
                acc = __builtin_amdgcn_mfma_f32_16x16x32_bf16(a1v, bf1, acc, 0, 0, 0);
                if (hh < 8) {
                    int j0 = (jt << 8) + (mt << 4) + ((lane >> 4) << 2);
                    u16x4 ow;
#pragma unroll
                    for (int r = 0; r < 4; r++)
                        ow[r] = f2h(fmaxf(acc[r] + bGh, 1e-6f) * 1024.0f);
                    *(u16x4*)&Wp[((size_t)((b << 3) + hh) << 18) + ((size_t)ii << 9) + j0] = ow;
                }
            }
            __syncthreads();
        }
    }

    gsync(&bars[0]);

    // ===== phase 1: projection GEMMs (768 tiles, 1:1 with blocks) =====
    {
        const int z = bid >> 8;                 // 0=Q 1=K 2=V
        const int rem = bid & 255;
        const int m0 = (rem >> 3) << 6, n0 = (rem & 7) << 6;
        const int wr = wave >> 1, wc = wave & 1;
        const u16* A  = Xall + (size_t)z * 1048576;
        const u16* Bm = Wall + (size_t)z * 262144;
        const float* bias = (z == 0) ? bq : (z == 1) ? bk : bv;
        u16* out = (z == 0) ? Qb : (z == 1) ? Kb : VT;

        f32x4 acc[2][2] = {};
        const int srow = t >> 2, scol = (t & 3) * 8;

        for (int k0 = 0; k0 < 512; k0 += 32) {
            gload_lds16(&A[(size_t)(m0 + srow) * 512 + k0 + scol], &sh.g.As[t * 8]);
            gload_lds16(&Bm[(size_t)(n0 + srow) * 512 + k0 + scol], &sh.g.Bs[t * 8]);
            __syncthreads();
            short8 af[2], bfr[2];
#pragma unroll
            for (int i = 0; i < 2; i++)
                af[i] = *(const short8*)&sh.g.As[(wr * 32 + i * 16 + (lane & 15)) * 32 + ((lane >> 4) << 3)];
#pragma unroll
            for (int jj = 0; jj < 2; jj++)
                bfr[jj] = *(const short8*)&sh.g.Bs[(wc * 32 + jj * 16 + (lane & 15)) * 32 + ((lane >> 4) << 3)];
#pragma unroll
            for (int i = 0; i < 2; i++)
#pragma unroll
                for (int jj = 0; jj < 2; jj++)
                    acc[i][jj] = __builtin_amdgcn_mfma_f32_16x16x32_bf16(af[i], bfr[jj], acc[i][jj], 0, 0, 0);
            __syncthreads();
        }
#pragma unroll
        for (int i = 0; i < 2; i++)
#pragma unroll
            for (int jj = 0; jj < 2; jj++)
#pragma unroll
                for (int r = 0; r < 4; r++) {
                    int row = m0 + wr * 32 + i * 16 + ((lane >> 4) << 2) + r;
                    int col = n0 + wc * 32 + jj * 16 + (lane & 15);
                    float v = acc[i][jj][r] + bias[col];
                    int b = row >> 9, rr = row & 511, h = col >> 6, d = col & 63;
                    if (z < 2)
                        out[(size_t)((((b << 3) + h) << 9) + rr) * 64 + d] = f2b(v);
                    else
                        out[(size_t)((((b << 3) + h) << 6) + d) * 512 + rr] = f2b(v);
                }
    }

    gsync(&bars[1]);

    // ===== phase 2: fused flash attention (1024 units, grid-stride) =====
    for (u32 u = (u32)bid; u < 1024u; u += NBLK) {
        const int c = lane & 15, g = lane >> 4;
        const int qb = (int)(u & 31u), bh = (int)(u >> 5);
        const int b = bh >> 3, h = bh & 7;
        const int q0 = qb << 4;

        const u16* Qp = Qb + ((size_t)bh << 15);
        const u16* Kp = Kb + ((size_t)bh << 15);
        const u16* Vp = VT + ((size_t)bh << 15);
        const _Float16* Bp = (const _Float16*)Wp + ((size_t)bh << 18) + ((size_t)q0 << 9);

        short8 qf[2];
#pragma unroll
        for (int ks = 0; ks < 2; ks++)
            qf[ks] = *(const short8*)&Qp[(size_t)(q0 + c) * 64 + ks * 32 + g * 8];

        f32x4 o[4] = {};
        float m[4] = {-1e30f, -1e30f, -1e30f, -1e30f};
        float l[4] = {0.f, 0.f, 0.f, 0.f};

        for (int kt = 0; kt < 2; kt++) {
            const int k0 = ((wave << 1) + kt) << 6;
            short8 kf[4][2], vf[4][2];
#pragma unroll
            for (int jj = 0; jj < 4; jj++)
#pragma unroll
                for (int ks = 0; ks < 2; ks++) {
                    kf[jj][ks] = *(const short8*)&Kp[(size_t)(k0 + jj * 16 + c) * 64 + ks * 32 + g * 8];
                    vf[jj][ks] = *(const short8*)&Vp[(size_t)(jj * 16 + c) * 512 + k0 + ks * 32 + g * 8];
                }
            float wgt[4][4];
#pragma unroll
            for (int jj = 0; jj < 4; jj++)
#pragma unroll
                for (int r = 0; r < 4; r++)
                    wgt[jj][r] = (float)Bp[(size_t)(g * 4 + r) * 512 + k0 + jj * 16 + c];

            f32x4 sa[4] = {};
            __builtin_amdgcn_s_setprio(1);
#pragma unroll
            for (int jj = 0; jj < 4; jj++)
#pragma unroll
                for (int ks = 0; ks < 2; ks++)
                    sa[jj] = __builtin_amdgcn_mfma_f32_16x16x32_bf16(qf[ks], kf[jj][ks], sa[jj], 0, 0, 0);
            __builtin_amdgcn_s_setprio(0);

            float s[4][4];
#pragma unroll
            for (int r = 0; r < 4; r++) {
#pragma unroll
                for (int jj = 0; jj < 4; jj++)
                    s[jj][r] = sa[jj][r] * 0.125f;
                float v = fmaxf(fmaxf(s[0][r], s[1][r]), fmaxf(s[2][r], s[3][r]));
#pragma unroll
                for (int off = 1; off < 16; off <<= 1)
                    v = fmaxf(v, __shfl_xor(v, off));
                float mn = fmaxf(m[r], v);
                float alpha = __expf(m[r] - mn);
                m[r] = mn;
                float rs = 0.f;
#pragma unroll
                for (int jj = 0; jj < 4; jj++) {
                    float p = wgt[jj][r] * __expf(s[jj][r] - mn);
                    s[jj][r] = p;
                    rs += p;
                }
#pragma unroll
                for (int off = 1; off < 16; off <<= 1)
                    rs += __shfl_xor(rs, off);
                l[r] = l[r] * alpha + rs;
#pragma unroll
                for (int jjo = 0; jjo < 4; jjo++)
                    o[jjo][r] *= alpha;
            }

#pragma unroll
            for (int jj = 0; jj < 4; jj++)
#pragma unroll
                for (int r = 0; r < 4; r++)
                    sh.a.Pl[wave][(g * 4 + r) * 68 + jj * 16 + c] = f2b(s[jj][r]);
            asm volatile("s_waitcnt lgkmcnt(0)" ::: "memory");
            __builtin_amdgcn_sched_barrier(0);

            short8 pa[2];
#pragma unroll
            for (int ks = 0; ks < 2; ks++)
                pa[ks] = *(const short8*)&sh.a.Pl[wave][c * 68 + ks * 32 + g * 8];
            __builtin_amdgcn_s_setprio(1);
#pragma unroll
            for (int jjo = 0; jjo < 4; jjo++)
#pragma unroll
                for (int ks = 0; ks < 2; ks++)
                    o[jjo] = __builtin_amdgcn_mfma_f32_16x16x32_bf16(pa[ks], vf[jjo][ks], o[jjo], 0, 0, 0);
            __builtin_amdgcn_s_setprio(0);
            __builtin_amdgcn_sched_barrier(0);
        }

        if (wave > 0) {
#pragma unroll
            for (int r = 0; r < 4; r++) {
                sh.a.Mrg[wave - 1][lane][r] = m[r];
                sh.a.Mrg[wave - 1][lane][4 + r] = l[r];
#pragma unroll
                for (int jjo = 0; jjo < 4; jjo++)
                    sh.a.Mrg[wave - 1][lane][8 + jjo * 4 + r] = o[jjo][r];
            }
        }
        __syncthreads();
        if (wave == 0) {
#pragma unroll
            for (int w = 0; w < 3; w++) {
#pragma unroll
                for (int r = 0; r < 4; r++) {
                    float m1 = sh.a.Mrg[w][lane][r];
                    float l1 = sh.a.Mrg[w][lane][4 + r];
                    float mn = fmaxf(m[r], m1);
                    float a0 = __expf(m[r] - mn), a1 = __expf(m1 - mn);
                    m[r] = mn;
                    l[r] = l[r] * a0 + l1 * a1;
#pragma unroll
                    for (int jjo = 0; jjo < 4; jjo++)
                        o[jjo][r] = o[jjo][r] * a0 + sh.a.Mrg[w][lane][8 + jjo * 4 + r] * a1;
                }
            }
#pragma unroll
            for (int r = 0; r < 4; r++) {
                float inv_l = 1.0f / l[r];
                int row = q0 + g * 4 + r;
#pragma unroll
                for (int jjo = 0; jjo < 4; jjo++)
                    ATT[(size_t)(((b << 9) + row) << 9) + (h << 6) + jjo * 16 + c] = f2b(o[jjo][r] * inv_l);
            }
        }
        __syncthreads();   // Mrg reuse across grid-stride iterations
    }

    gsync(&bars[2]);

    // ===== phase 3: output GEMM (256 tiles on blocks 0..255) =====
    if (bid < 256) {
        const int m0 = (bid >> 3) << 6, n0 = (bid & 7) << 6;
        const int wr = wave >> 1, wc = wave & 1;
        const u16* A  = ATT;
        const u16* Bm = Wall + 786432;          // Wo bf16
        f32x4 acc[2][2] = {};
        const int srow = t >> 2, scol = (t & 3) * 8;

        for (int k0 = 0; k0 < 512; k0 += 32) {
            gload_lds16(&A[(size_t)(m0 + srow) * 512 + k0 + scol], &sh.g.As[t * 8]);
            gload_lds16(&Bm[(size_t)(n0 + srow) * 512 + k0 + scol], &sh.g.Bs[t * 8]);
            __syncthreads();
            short8 af[2], bfr[2];
#pragma unroll
            for (int i = 0; i < 2; i++)
                af[i] = *(const short8*)&sh.g.As[(wr * 32 + i * 16 + (lane & 15)) * 32 + ((lane >> 4) << 3)];
#pragma unroll
            for (int jj = 0; jj < 2; jj++)
                bfr[jj] = *(const short8*)&sh.g.Bs[(wc * 32 + jj * 16 + (lane & 15)) * 32 + ((lane >> 4) << 3)];
#pragma unroll
            for (int i = 0; i < 2; i++)
#pragma unroll
                for (int jj = 0; jj < 2; jj++)
                    acc[i][jj] = __builtin_amdgcn_mfma_f32_16x16x32_bf16(af[i], bfr[jj], acc[i][jj], 0, 0, 0);
            __syncthreads();
        }
#pragma unroll
        for (int i = 0; i < 2; i++)
#pragma unroll
            for (int jj = 0; jj < 2; jj++)
#pragma unroll
                for (int r = 0; r < 4; r++) {
                    int row = m0 + wr * 32 + i * 16 + ((lane >> 4) << 2) + r;
                    int col = n0 + wc * 32 + jj * 16 + (lane & 15);
                    outF[((size_t)row << 9) + col] = acc[i][jj][r] + bo[col];
                }
    }
}

// ---------- launch ----------
extern "C" void kernel_launch(void* const* d_in, const int* in_sizes, int n_in,
                              void* d_out, int out_size, void* d_ws, size_t ws_size,
                              hipStream_t stream) {
    const float* inq = (const float*)d_in[0];
    const float* ink = (const float*)d_in[1];
    const float* inv = (const float*)d_in[2];
    const float* box = (const float*)d_in[3];
    const float* Wq  = (const float*)d_in[4];
    const float* bq  = (const float*)d_in[5];
    const float* Wk  = (const float*)d_in[6];
    const float* bk  = (const float*)d_in[7];
    const float* Wv  = (const float*)d_in[8];
    const float* bv  = (const float*)d_in[9];
    const float* Wo  = (const float*)d_in[10];
    const float* bo  = (const float*)d_in[11];
    const float* WG  = (const float*)d_in[12];
    const float* bG  = (const float*)d_in[13];

    u16* base = (u16*)d_ws;
    u16* Xall = base;                    // XQ,XK,XV bf16 (3 x 1,048,576)
    u16* Wall = base + 3145728;          // WQb,WKb,WVb,WOb bf16 (4 x 262,144)
    u16* Qb   = base + 4194304;          // [B,H,N,64] bf16
    u16* Kb   = base + 5242880;          // [B,H,N,64] bf16
    u16* VT   = base + 6291456;          // [B,H,64,N] bf16
    u16* ATT  = base + 7340032;          // [B,N,512] bf16
    u16* Wp   = base + 8388608;          // [B,H,N,N] f16 geometry weights
    u32* bars = (u32*)(base + 20971520); // 3 one-shot barrier counters @ 40 MiB

    hipMemsetAsync(bars, 0, 12, stream);
    fused_k<<<dim3(NBLK), dim3(256), 0, stream>>>(
        inq, ink, inv, box, Wq, bq, Wk, bk, Wv, bv, Wo, bo, WG, bG,
        Xall, Wall, Qb, Kb, VT, ATT, Wp, (float*)d_out, bars);
}

// Round 9
// 330.080 us; speedup vs baseline: 1.3067x; 1.3067x over previous
//
#include <hip/hip_runtime.h>
#include <hip/hip_bf16.h>
#include <cstdint>

typedef unsigned short u16;
typedef unsigned int u32;
typedef __attribute__((ext_vector_type(8))) short short8;   // 8 bf16 MFMA A/B frag
typedef __attribute__((ext_vector_type(4))) float f32x4;    // MFMA C/D frag
typedef __attribute__((ext_vector_type(4))) unsigned int u32x4;
typedef __attribute__((ext_vector_type(4))) unsigned short u16x4;

#define REV 15.91549431f   // 100/(2*pi)
#define NBLK 512u          // 2 blocks/CU x 256 CUs — guaranteed co-residency at 256 VGPR

// ---------- helpers ----------
__device__ __forceinline__ u16 f2b(float x) { return __builtin_bit_cast(u16, (__bf16)x); }
__device__ __forceinline__ u16 f2h(float x) { return __builtin_bit_cast(u16, (_Float16)x); }
__device__ __forceinline__ float c_dim_f(int f) {
    const float c[8] = {1.0f, 0.42169650f, 0.17782794f, 0.074989421f,
                        0.031622777f, 0.013335214f, 0.0056234132f, 0.0023713737f};
    return c[f];
}
__device__ __forceinline__ void gload_lds16(const void* g, void* l) {
    __builtin_amdgcn_global_load_lds((const __attribute__((address_space(1))) u32*)g,
                                     (__attribute__((address_space(3))) u32*)l, 16, 0, 0);
}

union SharedMem {
    char embs[256 * 128];                                   // geom: [256 pairs][64 bf16]
    struct { u16 As[64 * 32]; u16 Bs[64 * 32]; } g;         // GEMM staging
    struct { u16 Pl[4][16 * 68]; float Mrg[3][64][25]; } a; // attn
};

// one-shot grid barrier: arrive, spin to NBLK. Agent-scope atomics + fences.
__device__ __forceinline__ void gsync(u32* c) {
    __syncthreads();
    if (threadIdx.x == 0) {
        __threadfence();   // release
        __hip_atomic_fetch_add(c, 1u, __ATOMIC_ACQ_REL, __HIP_MEMORY_SCOPE_AGENT);
        while (__hip_atomic_load(c, __ATOMIC_ACQUIRE, __HIP_MEMORY_SCOPE_AGENT) < NBLK)
            __builtin_amdgcn_s_sleep(2);
        __threadfence();   // acquire
    }
    __syncthreads();
}

__global__ __launch_bounds__(256, 2) void fused_k(
        const float* __restrict__ inq, const float* __restrict__ ink,
        const float* __restrict__ inv, const float* __restrict__ box,
        const float* __restrict__ Wq, const float* __restrict__ bq,
        const float* __restrict__ Wk, const float* __restrict__ bk,
        const float* __restrict__ Wv, const float* __restrict__ bv,
        const float* __restrict__ Wo, const float* __restrict__ bo,
        const float* __restrict__ WG, const float* __restrict__ bG,
        u16* __restrict__ Xall, u16* __restrict__ Wall,
        u16* __restrict__ Qb, u16* __restrict__ Kb, u16* __restrict__ VT,
        u16* __restrict__ ATT, u16* __restrict__ Wp,
        float* __restrict__ outF, u32* __restrict__ bars) {
    __shared__ SharedMem sh;
    const int t = threadIdx.x;
    const int wave = t >> 6, lane = t & 63;
    const int bid = blockIdx.x;

    // ===== phase 0a: f32 -> bf16 conversion (grid-stride, no ptr arrays) =====
    for (u32 idx = (u32)bid * 256u + (u32)t; idx < 1048576u; idx += NBLK * 256u) {
        const float* s; u16* dst; u32 off;
        if (idx < 786432u) {                       // X: 3 x 262144 float4
            u32 z = idx >> 18; off = (idx & 262143u) << 2;
            s = (z == 0) ? inq : (z == 1) ? ink : inv;
            dst = Xall + ((size_t)z << 20) + off;
        } else {                                   // W: 4 x 65536 float4
            u32 w = idx - 786432u; u32 z = w >> 16; off = (w & 65535u) << 2;
            s = (z == 0) ? Wq : (z == 1) ? Wk : (z == 2) ? Wv : Wo;
            dst = Wall + ((size_t)z << 18) + off;
        }
        float4 v = *(const float4*)&s[off];
        u16x4 o = { f2b(v.x), f2b(v.y), f2b(v.z), f2b(v.w) };
        *(u16x4*)dst = o;
    }

    // ===== phase 0b: geometry weights w = 1024*max(relu(emb@WG+bG),1e-6) f16 =====
    {
        const int hh = lane & 15;
        const int ko = (lane >> 4) << 3;
        short8 bf0 = {0,0,0,0,0,0,0,0}, bf1 = {0,0,0,0,0,0,0,0};
        float bGh = 0.0f;
        if (hh < 8) {
            const float* wrow = WG + hh * 64;
#pragma unroll
            for (int e = 0; e < 8; e++) {
                bf0[e] = (short)f2b(wrow[ko + e]);
                bf1[e] = (short)f2b(wrow[32 + ko + e]);
            }
            bGh = bG[hh];
        }
        for (u32 u = (u32)bid; u < 4096u; u += NBLK) {
            const int b = (int)(u >> 10);
            const int ii = (int)((u & 1023u) >> 1);
            const int jt = (int)(u & 1u);
            const int j = (jt << 8) + t;
            const int swz = (t & 7) << 4;

            float4 bi = *(const float4*)&box[(size_t)(((b << 9) + ii) << 2)];
            float4 bj = *(const float4*)&box[(size_t)(((b << 9) + j) << 2)];
            float cxi = (bi.x + bi.z) * 0.5f, cyi = (bi.y + bi.w) * 0.5f;
            float wdi = bi.z - bi.x + 1.0f,  hgi = bi.w - bi.y + 1.0f;
            float cxj = (bj.x + bj.z) * 0.5f, cyj = (bj.y + bj.w) * 0.5f;
            float wdj = bj.z - bj.x + 1.0f,  hgj = bj.w - bj.y + 1.0f;

            float pos[4];
            pos[0] = __logf(fmaxf(fabsf((cxi - cxj) / wdi), 1e-3f));
            pos[1] = __logf(fmaxf(fabsf((cyi - cyj) / hgi), 1e-3f));
            pos[2] = __logf(wdi) - __logf(wdj);
            pos[3] = __logf(hgi) - __logf(hgj);

#pragma unroll
            for (int p = 0; p < 4; p++) {
                float rev = pos[p] * REV;
                u32x4 sp, cp;
#pragma unroll
                for (int f = 0; f < 4; f++) {
                    float a0 = rev * c_dim_f(2 * f), a1 = rev * c_dim_f(2 * f + 1);
                    sp[f] = (u32)f2b(__builtin_amdgcn_sinf(a0)) | ((u32)f2b(__builtin_amdgcn_sinf(a1)) << 16);
                    cp[f] = (u32)f2b(__builtin_amdgcn_cosf(a0)) | ((u32)f2b(__builtin_amdgcn_cosf(a1)) << 16);
                }
                *(u32x4*)(sh.embs + (((t << 7) + (p << 4)) ^ swz)) = sp;
                *(u32x4*)(sh.embs + (((t << 7) + 64 + (p << 4)) ^ swz)) = cp;
            }
            __syncthreads();

#pragma unroll
            for (int tt = 0; tt < 4; tt++) {
                int mt = (wave << 2) + tt;
                int row = (mt << 4) + hh;
                int rswz = (row & 7) << 4;
                short8 a0v = *(const short8*)(sh.embs + (((row << 7) + (ko << 1)) ^ rswz));
                short8 a1v = *(const short8*)(sh.embs + (((row << 7) + 64 + (ko << 1)) ^ rswz));
                f32x4 acc = {0.f, 0.f, 0.f, 0.f};
                acc = __builtin_amdgcn_mfma_f32_16x16x32_bf16(a0v, bf0, acc, 0, 0, 0);
                acc = __builtin_amdgcn_mfma_f32_16x16x32_bf16(a1v, bf1, acc, 0, 0, 0);
                if (hh < 8) {
                    int j0 = (jt << 8) + (mt << 4) + ((lane >> 4) << 2);
                    u16x4 ow;
#pragma unroll
                    for (int r = 0; r < 4; r++)
                        ow[r] = f2h(fmaxf(acc[r] + bGh, 1e-6f) * 1024.0f);
                    *(u16x4*)&Wp[((size_t)((b << 3) + hh) << 18) + ((size_t)ii << 9) + j0] = ow;
                }
            }
            __syncthreads();
        }
    }

    gsync(&bars[0]);

    // ===== phase 1: projection GEMMs (768 tiles, grid-stride) =====
    for (u32 u = (u32)bid; u < 768u; u += NBLK) {
        const int z = (int)(u >> 8);            // 0=Q 1=K 2=V
        const int rem = (int)(u & 255u);
        const int m0 = (rem >> 3) << 6, n0 = (rem & 7) << 6;
        const int wr = wave >> 1, wc = wave & 1;
        const u16* A  = Xall + (size_t)z * 1048576;
        const u16* Bm = Wall + (size_t)z * 262144;
        const float* bias = (z == 0) ? bq : (z == 1) ? bk : bv;
        u16* out = (z == 0) ? Qb : (z == 1) ? Kb : VT;

        f32x4 acc[2][2] = {};
        const int srow = t >> 2, scol = (t & 3) * 8;

        for (int k0 = 0; k0 < 512; k0 += 32) {
            gload_lds16(&A[(size_t)(m0 + srow) * 512 + k0 + scol], &sh.g.As[t * 8]);
            gload_lds16(&Bm[(size_t)(n0 + srow) * 512 + k0 + scol], &sh.g.Bs[t * 8]);
            __syncthreads();
            short8 af[2], bfr[2];
#pragma unroll
            for (int i = 0; i < 2; i++)
                af[i] = *(const short8*)&sh.g.As[(wr * 32 + i * 16 + (lane & 15)) * 32 + ((lane >> 4) << 3)];
#pragma unroll
            for (int jj = 0; jj < 2; jj++)
                bfr[jj] = *(const short8*)&sh.g.Bs[(wc * 32 + jj * 16 + (lane & 15)) * 32 + ((lane >> 4) << 3)];
#pragma unroll
            for (int i = 0; i < 2; i++)
#pragma unroll
                for (int jj = 0; jj < 2; jj++)
                    acc[i][jj] = __builtin_amdgcn_mfma_f32_16x16x32_bf16(af[i], bfr[jj], acc[i][jj], 0, 0, 0);
            __syncthreads();
        }
#pragma unroll
        for (int i = 0; i < 2; i++)
#pragma unroll
            for (int jj = 0; jj < 2; jj++)
#pragma unroll
                for (int r = 0; r < 4; r++) {
                    int row = m0 + wr * 32 + i * 16 + ((lane >> 4) << 2) + r;
                    int col = n0 + wc * 32 + jj * 16 + (lane & 15);
                    float v = acc[i][jj][r] + bias[col];
                    int b = row >> 9, rr = row & 511, h = col >> 6, d = col & 63;
                    if (z < 2)
                        out[(size_t)((((b << 3) + h) << 9) + rr) * 64 + d] = f2b(v);
                    else
                        out[(size_t)((((b << 3) + h) << 6) + d) * 512 + rr] = f2b(v);
                }
    }

    gsync(&bars[1]);

    // ===== phase 2: fused flash attention (1024 units, grid-stride) =====
    for (u32 u = (u32)bid; u < 1024u; u += NBLK) {
        const int c = lane & 15, g = lane >> 4;
        const int qb = (int)(u & 31u), bh = (int)(u >> 5);
        const int b = bh >> 3, h = bh & 7;
        const int q0 = qb << 4;

        const u16* Qp = Qb + ((size_t)bh << 15);
        const u16* Kp = Kb + ((size_t)bh << 15);
        const u16* Vp = VT + ((size_t)bh << 15);
        const _Float16* Bp = (const _Float16*)Wp + ((size_t)bh << 18) + ((size_t)q0 << 9);

        short8 qf[2];
#pragma unroll
        for (int ks = 0; ks < 2; ks++)
            qf[ks] = *(const short8*)&Qp[(size_t)(q0 + c) * 64 + ks * 32 + g * 8];

        f32x4 o[4] = {};
        float m[4] = {-1e30f, -1e30f, -1e30f, -1e30f};
        float l[4] = {0.f, 0.f, 0.f, 0.f};

        for (int kt = 0; kt < 2; kt++) {
            const int k0 = ((wave << 1) + kt) << 6;
            short8 kf[4][2], vf[4][2];
#pragma unroll
            for (int jj = 0; jj < 4; jj++)
#pragma unroll
                for (int ks = 0; ks < 2; ks++) {
                    kf[jj][ks] = *(const short8*)&Kp[(size_t)(k0 + jj * 16 + c) * 64 + ks * 32 + g * 8];
                    vf[jj][ks] = *(const short8*)&Vp[(size_t)(jj * 16 + c) * 512 + k0 + ks * 32 + g * 8];
                }
            float wgt[4][4];
#pragma unroll
            for (int jj = 0; jj < 4; jj++)
#pragma unroll
                for (int r = 0; r < 4; r++)
                    wgt[jj][r] = (float)Bp[(size_t)(g * 4 + r) * 512 + k0 + jj * 16 + c];

            f32x4 sa[4] = {};
            __builtin_amdgcn_s_setprio(1);
#pragma unroll
            for (int jj = 0; jj < 4; jj++)
#pragma unroll
                for (int ks = 0; ks < 2; ks++)
                    sa[jj] = __builtin_amdgcn_mfma_f32_16x16x32_bf16(qf[ks], kf[jj][ks], sa[jj], 0, 0, 0);
            __builtin_amdgcn_s_setprio(0);

            float s[4][4];
#pragma unroll
            for (int r = 0; r < 4; r++) {
#pragma unroll
                for (int jj = 0; jj < 4; jj++)
                    s[jj][r] = sa[jj][r] * 0.125f;
                float v = fmaxf(fmaxf(s[0][r], s[1][r]), fmaxf(s[2][r], s[3][r]));
#pragma unroll
                for (int off = 1; off < 16; off <<= 1)
                    v = fmaxf(v, __shfl_xor(v, off));
                float mn = fmaxf(m[r], v);
                float alpha = __expf(m[r] - mn);
                m[r] = mn;
                float rs = 0.f;
#pragma unroll
                for (int jj = 0; jj < 4; jj++) {
                    float p = wgt[jj][r] * __expf(s[jj][r] - mn);
                    s[jj][r] = p;
                    rs += p;
                }
#pragma unroll
                for (int off = 1; off < 16; off <<= 1)
                    rs += __shfl_xor(rs, off);
                l[r] = l[r] * alpha + rs;
#pragma unroll
                for (int jjo = 0; jjo < 4; jjo++)
                    o[jjo][r] *= alpha;
            }

#pragma unroll
            for (int jj = 0; jj < 4; jj++)
#pragma unroll
                for (int r = 0; r < 4; r++)
                    sh.a.Pl[wave][(g * 4 + r) * 68 + jj * 16 + c] = f2b(s[jj][r]);
            asm volatile("s_waitcnt lgkmcnt(0)" ::: "memory");
            __builtin_amdgcn_sched_barrier(0);

            short8 pa[2];
#pragma unroll
            for (int ks = 0; ks < 2; ks++)
                pa[ks] = *(const short8*)&sh.a.Pl[wave][c * 68 + ks * 32 + g * 8];
            __builtin_amdgcn_s_setprio(1);
#pragma unroll
            for (int jjo = 0; jjo < 4; jjo++)
#pragma unroll
                for (int ks = 0; ks < 2; ks++)
                    o[jjo] = __builtin_amdgcn_mfma_f32_16x16x32_bf16(pa[ks], vf[jjo][ks], o[jjo], 0, 0, 0);
            __builtin_amdgcn_s_setprio(0);
            __builtin_amdgcn_sched_barrier(0);
        }

        if (wave > 0) {
#pragma unroll
            for (int r = 0; r < 4; r++) {
                sh.a.Mrg[wave - 1][lane][r] = m[r];
                sh.a.Mrg[wave - 1][lane][4 + r] = l[r];
#pragma unroll
                for (int jjo = 0; jjo < 4; jjo++)
                    sh.a.Mrg[wave - 1][lane][8 + jjo * 4 + r] = o[jjo][r];
            }
        }
        __syncthreads();
        if (wave == 0) {
#pragma unroll
            for (int w = 0; w < 3; w++) {
#pragma unroll
                for (int r = 0; r < 4; r++) {
                    float m1 = sh.a.Mrg[w][lane][r];
                    float l1 = sh.a.Mrg[w][lane][4 + r];
                    float mn = fmaxf(m[r], m1);
                    float a0 = __expf(m[r] - mn), a1 = __expf(m1 - mn);
                    m[r] = mn;
                    l[r] = l[r] * a0 + l1 * a1;
#pragma unroll
                    for (int jjo = 0; jjo < 4; jjo++)
                        o[jjo][r] = o[jjo][r] * a0 + sh.a.Mrg[w][lane][8 + jjo * 4 + r] * a1;
                }
            }
#pragma unroll
            for (int r = 0; r < 4; r++) {
                float inv_l = 1.0f / l[r];
                int row = q0 + g * 4 + r;
#pragma unroll
                for (int jjo = 0; jjo < 4; jjo++)
                    ATT[(size_t)(((b << 9) + row) << 9) + (h << 6) + jjo * 16 + c] = f2b(o[jjo][r] * inv_l);
            }
        }
        __syncthreads();   // Mrg reuse across grid-stride iterations
    }

    gsync(&bars[2]);

    // ===== phase 3: output GEMM (256 tiles on blocks 0..255) =====
    if (bid < 256) {
        const int m0 = (bid >> 3) << 6, n0 = (bid & 7) << 6;
        const int wr = wave >> 1, wc = wave & 1;
        const u16* A  = ATT;
        const u16* Bm = Wall + 786432;          // Wo bf16
        f32x4 acc[2][2] = {};
        const int srow = t >> 2, scol = (t & 3) * 8;

        for (int k0 = 0; k0 < 512; k0 += 32) {
            gload_lds16(&A[(size_t)(m0 + srow) * 512 + k0 + scol], &sh.g.As[t * 8]);
            gload_lds16(&Bm[(size_t)(n0 + srow) * 512 + k0 + scol], &sh.g.Bs[t * 8]);
            __syncthreads();
            short8 af[2], bfr[2];
#pragma unroll
            for (int i = 0; i < 2; i++)
                af[i] = *(const short8*)&sh.g.As[(wr * 32 + i * 16 + (lane & 15)) * 32 + ((lane >> 4) << 3)];
#pragma unroll
            for (int jj = 0; jj < 2; jj++)
                bfr[jj] = *(const short8*)&sh.g.Bs[(wc * 32 + jj * 16 + (lane & 15)) * 32 + ((lane >> 4) << 3)];
#pragma unroll
            for (int i = 0; i < 2; i++)
#pragma unroll
                for (int jj = 0; jj < 2; jj++)
                    acc[i][jj] = __builtin_amdgcn_mfma_f32_16x16x32_bf16(af[i], bfr[jj], acc[i][jj], 0, 0, 0);
            __syncthreads();
        }
#pragma unroll
        for (int i = 0; i < 2; i++)
#pragma unroll
            for (int jj = 0; jj < 2; jj++)
#pragma unroll
                for (int r = 0; r < 4; r++) {
                    int row = m0 + wr * 32 + i * 16 + ((lane >> 4) << 2) + r;
                    int col = n0 + wc * 32 + jj * 16 + (lane & 15);
                    outF[((size_t)row << 9) + col] = acc[i][jj][r] + bo[col];
                }
    }
}

// ---------- launch ----------
extern "C" void kernel_launch(void* const* d_in, const int* in_sizes, int n_in,
                              void* d_out, int out_size, void* d_ws, size_t ws_size,
                              hipStream_t stream) {
    const float* inq = (const float*)d_in[0];
    const float* ink = (const float*)d_in[1];
    const float* inv = (const float*)d_in[2];
    const float* box = (const float*)d_in[3];
    const float* Wq  = (const float*)d_in[4];
    const float* bq  = (const float*)d_in[5];
    const float* Wk  = (const float*)d_in[6];
    const float* bk  = (const float*)d_in[7];
    const float* Wv  = (const float*)d_in[8];
    const float* bv  = (const float*)d_in[9];
    const float* Wo  = (const float*)d_in[10];
    const float* bo  = (const float*)d_in[11];
    const float* WG  = (const float*)d_in[12];
    const float* bG  = (const float*)d_in[13];

    u16* base = (u16*)d_ws;
    u16* Xall = base;                    // XQ,XK,XV bf16 (3 x 1,048,576)
    u16* Wall = base + 3145728;          // WQb,WKb,WVb,WOb bf16 (4 x 262,144)
    u16* Qb   = base + 4194304;          // [B,H,N,64] bf16
    u16* Kb   = base + 5242880;          // [B,H,N,64] bf16
    u16* VT   = base + 6291456;          // [B,H,64,N] bf16
    u16* ATT  = base + 7340032;          // [B,N,512] bf16
    u16* Wp   = base + 8388608;          // [B,H,N,N] f16 geometry weights
    u32* bars = (u32*)(base + 20971520); // 3 one-shot barrier counters @ 40 MiB

    hipMemsetAsync(bars, 0, 12, stream);
    fused_k<<<dim3(NBLK), dim3(256), 0, stream>>>(
        inq, ink, inv, box, Wq, bq, Wk, bk, Wv, bv, Wo, bo, WG, bG,
        Xall, Wall, Qb, Kb, VT, ATT, Wp, (float*)d_out, bars);
}

// Round 10
// 77.116 us; speedup vs baseline: 5.5931x; 4.2803x over previous
//
#include <hip/hip_runtime.h>
#include <hip/hip_bf16.h>
#include <cstdint>

typedef unsigned short u16;
typedef unsigned int u32;
typedef __attribute__((ext_vector_type(8))) short short8;   // 8 bf16 MFMA A/B frag
typedef __attribute__((ext_vector_type(4))) float f32x4;    // MFMA C/D frag
typedef __attribute__((ext_vector_type(4))) unsigned int u32x4;
typedef __attribute__((ext_vector_type(4))) unsigned short u16x4;

#define REV 15.91549431f   // 100/(2*pi): the "100*pos" angle in revolutions

// ---------- helpers ----------
__device__ __forceinline__ u16 f2b(float x) { return __builtin_bit_cast(u16, (__bf16)x); }
__device__ __forceinline__ u16 f2h(float x) { return __builtin_bit_cast(u16, (_Float16)x); }
__device__ __forceinline__ float h2f(u16 b) { return (float)__builtin_bit_cast(_Float16, b); }
__device__ __forceinline__ float c_dim_f(int f) {
    const float c[8] = {1.0f, 0.42169650f, 0.17782794f, 0.074989421f,
                        0.031622777f, 0.013335214f, 0.0056234132f, 0.0023713737f};
    return c[f];
}
__device__ __forceinline__ void gload_lds16(const void* g, void* l) {
    __builtin_amdgcn_global_load_lds((const __attribute__((address_space(1))) u32*)g,
                                     (__attribute__((address_space(3))) u32*)l, 16, 0, 0);
}

// ---------- per-box trig tables (SoA, f16-packed): T[f][box] = half2(sin,cos) ----------
// aw_f = log(w)*REV*c_dim[f] revolutions. Coalesced: lane j reads T[f][j].
__global__ __launch_bounds__(256) void table_k(const float* __restrict__ box,
                                               u32* __restrict__ TBw,
                                               u32* __restrict__ TBh) {
    int gid = blockIdx.x * 256 + threadIdx.x;          // 0..2047 boxes
    float4 bx = *(const float4*)&box[(size_t)gid * 4];
    float w = bx.z - bx.x + 1.0f, h = bx.w - bx.y + 1.0f;
    float lw = __logf(w) * REV, lh = __logf(h) * REV;
#pragma unroll
    for (int f = 0; f < 8; f++) {
        float aw = lw * c_dim_f(f), ah = lh * c_dim_f(f);
        TBw[f * 2048 + gid] = (u32)f2h(__builtin_amdgcn_sinf(aw))
                            | ((u32)f2h(__builtin_amdgcn_cosf(aw)) << 16);
        TBh[f * 2048 + gid] = (u32)f2h(__builtin_amdgcn_sinf(ah))
                            | ((u32)f2h(__builtin_amdgcn_cosf(ah)) << 16);
    }
}

// ---------- prep: f32->bf16 cvt (z 0..6) + geometry weights (z 7..10) ----------
// z 0..2: X inputs -> Xall;  z 3..6: weights -> Wall [x<256]
// z 7..10: geom b=z-7: w = 1024*max(relu(emb@WG+bG),1e-6) stored f16
// (consumed multiplicatively: softmax(log(w)+s) == normalized w*e^s).
// p=0,1: direct v_sin/v_cos. p=2,3: angle-difference from SoA tables
// (sin(A-B)=sA*cB-cA*sB) — i-side scalar loads, j-side coalesced.
__global__ __launch_bounds__(256) void prep_k(const float* __restrict__ s0,
                                              const float* __restrict__ s1,
                                              const float* __restrict__ s2,
                                              const float* __restrict__ s3,
                                              const float* __restrict__ s4,
                                              const float* __restrict__ s5,
                                              const float* __restrict__ s6,
                                              const float* __restrict__ box,
                                              const float* __restrict__ WG,
                                              const float* __restrict__ bG,
                                              const u32* __restrict__ TBw,
                                              const u32* __restrict__ TBh,
                                              u16* __restrict__ dstX,
                                              u16* __restrict__ dstW,
                                              u16* __restrict__ outW) {
    __shared__ char embs[256 * 128];   // [256 pairs][64 bf16] rows, 128B each
    const int z = blockIdx.z;
    const int t = threadIdx.x;

    if (z < 7) {
        const float* s;
        u16* dst;
        if (z < 3) {
            s = (z == 0) ? s0 : (z == 1) ? s1 : s2;
            dst = dstX + (size_t)z * 1048576;
        } else {
            if (blockIdx.x >= 256) return;
            s = (z == 3) ? s3 : (z == 4) ? s4 : (z == 5) ? s5 : s6;
            dst = dstW + (size_t)(z - 3) * 262144;
        }
        int i = (blockIdx.x * 256 + t) * 4;
        float4 v = *(const float4*)&s[i];
        u16x4 o = { f2b(v.x), f2b(v.y), f2b(v.z), f2b(v.w) };
        *(u16x4*)&dst[i] = o;
        return;
    }

    // ---------------- geometry ----------------
    const int wave = t >> 6, lane = t & 63;
    const int b = z - 7;
    const int jt = blockIdx.x & 1, ii = blockIdx.x >> 1;
    const int j = (jt << 8) + t;
    const int swz = (t & 7) << 4;
    const int gi = (b << 9) + ii;      // block-uniform box index
    const int gj = (b << 9) + j;       // per-lane box index

    float4 bi = *(const float4*)&box[(size_t)(gi << 2)];
    float4 bj = *(const float4*)&box[(size_t)(gj << 2)];
    float cxi = (bi.x + bi.z) * 0.5f, cyi = (bi.y + bi.w) * 0.5f;
    float wdi = bi.z - bi.x + 1.0f,   hgi = bi.w - bi.y + 1.0f;
    float cxj = (bj.x + bj.z) * 0.5f, cyj = (bj.y + bj.w) * 0.5f;

    float pos01[2];
    pos01[0] = __logf(fmaxf(fabsf((cxi - cxj) / wdi), 1e-3f));
    pos01[1] = __logf(fmaxf(fabsf((cyi - cyj) / hgi), 1e-3f));

    // ---- p = 0,1: direct trig ----
#pragma unroll
    for (int p = 0; p < 2; p++) {
        float rev = pos01[p] * REV;
        u32x4 sp, cp;
#pragma unroll
        for (int f = 0; f < 4; f++) {
            float a0 = rev * c_dim_f(2 * f), a1 = rev * c_dim_f(2 * f + 1);
            sp[f] = (u32)f2b(__builtin_amdgcn_sinf(a0)) | ((u32)f2b(__builtin_amdgcn_sinf(a1)) << 16);
            cp[f] = (u32)f2b(__builtin_amdgcn_cosf(a0)) | ((u32)f2b(__builtin_amdgcn_cosf(a1)) << 16);
        }
        *(u32x4*)(embs + (((t << 7) + (p << 4)) ^ swz)) = sp;
        *(u32x4*)(embs + (((t << 7) + 64 + (p << 4)) ^ swz)) = cp;
    }

    // ---- p = 2,3: angle difference from tables (no trans ops) ----
#pragma unroll
    for (int p = 2; p < 4; p++) {
        const u32* Tp = (p == 2) ? TBw : TBh;
        u32x4 sp, cp;
#pragma unroll
        for (int f4 = 0; f4 < 4; f4++) {
            u32 pj0 = Tp[(2 * f4) * 2048 + gj];        // coalesced
            u32 pj1 = Tp[(2 * f4 + 1) * 2048 + gj];
            u32 pi0 = Tp[(2 * f4) * 2048 + gi];        // scalar (uniform)
            u32 pi1 = Tp[(2 * f4 + 1) * 2048 + gi];
            float sj0 = h2f((u16)pj0), cj0 = h2f((u16)(pj0 >> 16));
            float sj1 = h2f((u16)pj1), cj1 = h2f((u16)(pj1 >> 16));
            float si0 = h2f((u16)pi0), ci0 = h2f((u16)(pi0 >> 16));
            float si1 = h2f((u16)pi1), ci1 = h2f((u16)(pi1 >> 16));
            float s0 = si0 * cj0 - ci0 * sj0;
            float s1 = si1 * cj1 - ci1 * sj1;
            float c0 = ci0 * cj0 + si0 * sj0;
            float c1 = ci1 * cj1 + si1 * sj1;
            sp[f4] = (u32)f2b(s0) | ((u32)f2b(s1) << 16);
            cp[f4] = (u32)f2b(c0) | ((u32)f2b(c1) << 16);
        }
        *(u32x4*)(embs + (((t << 7) + (p << 4)) ^ swz)) = sp;
        *(u32x4*)(embs + (((t << 7) + 64 + (p << 4)) ^ swz)) = cp;
    }

    const int hh = lane & 15;
    const int ko = (lane >> 4) << 3;
    short8 bf0 = {0,0,0,0,0,0,0,0}, bf1 = {0,0,0,0,0,0,0,0};
    float bGh = 0.0f;
    if (hh < 8) {
        const float* wrow = WG + hh * 64;
#pragma unroll
        for (int e = 0; e < 8; e++) {
            bf0[e] = (short)f2b(wrow[ko + e]);
            bf1[e] = (short)f2b(wrow[32 + ko + e]);
        }
        bGh = bG[hh];
    }
    __syncthreads();

#pragma unroll
    for (int tt = 0; tt < 4; tt++) {
        int mt = (wave << 2) + tt;
        int row = (mt << 4) + hh;
        int rswz = (row & 7) << 4;
        short8 a0v = *(const short8*)(embs + (((row << 7) + (ko << 1)) ^ rswz));
        short8 a1v = *(const short8*)(embs + (((row << 7) + 64 + (ko << 1)) ^ rswz));
        f32x4 acc = {0.f, 0.f, 0.f, 0.f};
        acc = __builtin_amdgcn_mfma_f32_16x16x32_bf16(a0v, bf0, acc, 0, 0, 0);
        acc = __builtin_amdgcn_mfma_f32_16x16x32_bf16(a1v, bf1, acc, 0, 0, 0);
        if (hh < 8) {
            int j0 = (jt << 8) + (mt << 4) + ((lane >> 4) << 2);
            u16x4 ow;
#pragma unroll
            for (int r = 0; r < 4; r++)
                ow[r] = f2h(fmaxf(acc[r] + bGh, 1e-6f) * 1024.0f);
            *(u16x4*)&outW[((size_t)((b << 3) + hh) << 18) + ((size_t)ii << 9) + j0] = ow;
        }
    }
}

// ---------- fused flash attention: p = w * e^(0.125*QK^T - m), O = PV/l ----------
__global__ __launch_bounds__(256) void attn_k(const u16* __restrict__ Qb,
                                              const u16* __restrict__ Kb,
                                              const u16* __restrict__ VT,
                                              const u16* __restrict__ Wp,
                                              u16* __restrict__ ATT) {
    __shared__ u16 Pl[4][16 * 68];
    __shared__ float Mrg[3][64][25];
    const int t = threadIdx.x;
    const int wave = t >> 6, lane = t & 63;
    const int c = lane & 15, g = lane >> 4;
    const int bid = blockIdx.x;
    const int qb = bid & 31, bh = bid >> 5;
    const int b = bh >> 3, h = bh & 7;
    const int q0 = qb << 4;

    const u16* Qp = Qb + ((size_t)bh << 15);
    const u16* Kp = Kb + ((size_t)bh << 15);
    const u16* Vp = VT + ((size_t)bh << 15);
    const _Float16* Bp = (const _Float16*)Wp + ((size_t)bh << 18) + ((size_t)q0 << 9);

    short8 qf[2];
#pragma unroll
    for (int ks = 0; ks < 2; ks++)
        qf[ks] = *(const short8*)&Qp[(size_t)(q0 + c) * 64 + ks * 32 + g * 8];

    f32x4 o[4] = {};
    float m[4] = {-1e30f, -1e30f, -1e30f, -1e30f};
    float l[4] = {0.f, 0.f, 0.f, 0.f};

    for (int kt = 0; kt < 2; kt++) {
        const int k0 = ((wave << 1) + kt) << 6;
        short8 kf[4][2], vf[4][2];
#pragma unroll
        for (int jj = 0; jj < 4; jj++)
#pragma unroll
            for (int ks = 0; ks < 2; ks++) {
                kf[jj][ks] = *(const short8*)&Kp[(size_t)(k0 + jj * 16 + c) * 64 + ks * 32 + g * 8];
                vf[jj][ks] = *(const short8*)&Vp[(size_t)(jj * 16 + c) * 512 + k0 + ks * 32 + g * 8];
            }
        float wgt[4][4];
#pragma unroll
        for (int jj = 0; jj < 4; jj++)
#pragma unroll
            for (int r = 0; r < 4; r++)
                wgt[jj][r] = (float)Bp[(size_t)(g * 4 + r) * 512 + k0 + jj * 16 + c];

        f32x4 sa[4] = {};
        __builtin_amdgcn_s_setprio(1);
#pragma unroll
        for (int jj = 0; jj < 4; jj++)
#pragma unroll
            for (int ks = 0; ks < 2; ks++)
                sa[jj] = __builtin_amdgcn_mfma_f32_16x16x32_bf16(qf[ks], kf[jj][ks], sa[jj], 0, 0, 0);
        __builtin_amdgcn_s_setprio(0);

        float s[4][4];
#pragma unroll
        for (int r = 0; r < 4; r++) {
#pragma unroll
            for (int jj = 0; jj < 4; jj++)
                s[jj][r] = sa[jj][r] * 0.125f;
            float v = fmaxf(fmaxf(s[0][r], s[1][r]), fmaxf(s[2][r], s[3][r]));
#pragma unroll
            for (int off = 1; off < 16; off <<= 1)
                v = fmaxf(v, __shfl_xor(v, off));
            float mn = fmaxf(m[r], v);
            float alpha = __expf(m[r] - mn);
            m[r] = mn;
            float rs = 0.f;
#pragma unroll
            for (int jj = 0; jj < 4; jj++) {
                float p = wgt[jj][r] * __expf(s[jj][r] - mn);
                s[jj][r] = p;
                rs += p;
            }
#pragma unroll
            for (int off = 1; off < 16; off <<= 1)
                rs += __shfl_xor(rs, off);
            l[r] = l[r] * alpha + rs;
#pragma unroll
            for (int jjo = 0; jjo < 4; jjo++)
                o[jjo][r] *= alpha;
        }

#pragma unroll
        for (int jj = 0; jj < 4; jj++)
#pragma unroll
            for (int r = 0; r < 4; r++)
                Pl[wave][(g * 4 + r) * 68 + jj * 16 + c] = f2b(s[jj][r]);
        asm volatile("s_waitcnt lgkmcnt(0)" ::: "memory");
        __builtin_amdgcn_sched_barrier(0);

        short8 pa[2];
#pragma unroll
        for (int ks = 0; ks < 2; ks++)
            pa[ks] = *(const short8*)&Pl[wave][c * 68 + ks * 32 + g * 8];
        __builtin_amdgcn_s_setprio(1);
#pragma unroll
        for (int jjo = 0; jjo < 4; jjo++)
#pragma unroll
            for (int ks = 0; ks < 2; ks++)
                o[jjo] = __builtin_amdgcn_mfma_f32_16x16x32_bf16(pa[ks], vf[jjo][ks], o[jjo], 0, 0, 0);
        __builtin_amdgcn_s_setprio(0);
        __builtin_amdgcn_sched_barrier(0);
    }

    if (wave > 0) {
#pragma unroll
        for (int r = 0; r < 4; r++) {
            Mrg[wave - 1][lane][r] = m[r];
            Mrg[wave - 1][lane][4 + r] = l[r];
#pragma unroll
            for (int jjo = 0; jjo < 4; jjo++)
                Mrg[wave - 1][lane][8 + jjo * 4 + r] = o[jjo][r];
        }
    }
    __syncthreads();
    if (wave == 0) {
#pragma unroll
        for (int w = 0; w < 3; w++) {
#pragma unroll
            for (int r = 0; r < 4; r++) {
                float m1 = Mrg[w][lane][r];
                float l1 = Mrg[w][lane][4 + r];
                float mn = fmaxf(m[r], m1);
                float a0 = __expf(m[r] - mn), a1 = __expf(m1 - mn);
                m[r] = mn;
                l[r] = l[r] * a0 + l1 * a1;
#pragma unroll
                for (int jjo = 0; jjo < 4; jjo++)
                    o[jjo][r] = o[jjo][r] * a0 + Mrg[w][lane][8 + jjo * 4 + r] * a1;
            }
        }
#pragma unroll
        for (int r = 0; r < 4; r++) {
            float inv = 1.0f / l[r];
            int row = q0 + g * 4 + r;
#pragma unroll
            for (int jjo = 0; jjo < 4; jjo++)
                ATT[(size_t)(((b << 9) + row) << 9) + (h << 6) + jjo * 16 + c] = f2b(o[jjo][r] * inv);
        }
    }
}

// ---------- merged projection GEMM (bf16, global_load_lds staging) ----------
__global__ __launch_bounds__(256) void proj_k(const u16* __restrict__ Xall,
                                              const u16* __restrict__ Wall,
                                              const float* __restrict__ bq,
                                              const float* __restrict__ bk,
                                              const float* __restrict__ bv,
                                              u16* __restrict__ Qb,
                                              u16* __restrict__ Kb,
                                              u16* __restrict__ VT) {
    __shared__ u16 As[64 * 32];
    __shared__ u16 Bs[64 * 32];

    const int t = threadIdx.x;
    const int wave = t >> 6, lane = t & 63;
    const int wr = wave >> 1, wc = wave & 1;
    const int m0 = blockIdx.y * 64, n0 = blockIdx.x * 64;
    const int z = blockIdx.z;

    const u16* A  = Xall + (size_t)z * 1048576;
    const u16* Bm = Wall + (size_t)z * 262144;
    const float* bias = (z == 0) ? bq : (z == 1) ? bk : bv;
    u16* out = (z == 0) ? Qb : (z == 1) ? Kb : VT;

    f32x4 acc[2][2] = {};
    const int srow = t >> 2, scol = (t & 3) * 8;

    for (int k0 = 0; k0 < 512; k0 += 32) {
        gload_lds16(&A[(size_t)(m0 + srow) * 512 + k0 + scol], &As[t * 8]);
        gload_lds16(&Bm[(size_t)(n0 + srow) * 512 + k0 + scol], &Bs[t * 8]);
        __syncthreads();
        short8 af[2], bfr[2];
#pragma unroll
        for (int i = 0; i < 2; i++)
            af[i] = *(const short8*)&As[(wr * 32 + i * 16 + (lane & 15)) * 32 + ((lane >> 4) << 3)];
#pragma unroll
        for (int jj = 0; jj < 2; jj++)
            bfr[jj] = *(const short8*)&Bs[(wc * 32 + jj * 16 + (lane & 15)) * 32 + ((lane >> 4) << 3)];
#pragma unroll
        for (int i = 0; i < 2; i++)
#pragma unroll
            for (int jj = 0; jj < 2; jj++)
                acc[i][jj] = __builtin_amdgcn_mfma_f32_16x16x32_bf16(af[i], bfr[jj], acc[i][jj], 0, 0, 0);
        __syncthreads();
    }

#pragma unroll
    for (int i = 0; i < 2; i++)
#pragma unroll
        for (int jj = 0; jj < 2; jj++)
#pragma unroll
            for (int r = 0; r < 4; r++) {
                int row = m0 + wr * 32 + i * 16 + ((lane >> 4) << 2) + r;
                int col = n0 + wc * 32 + jj * 16 + (lane & 15);
                float v = acc[i][jj][r] + bias[col];
                int b = row >> 9, rr = row & 511, h = col >> 6, d = col & 63;
                if (z < 2)
                    out[(size_t)((((b << 3) + h) << 9) + rr) * 64 + d] = f2b(v);
                else
                    out[(size_t)((((b << 3) + h) << 6) + d) * 512 + rr] = f2b(v);
            }
}

// ---------- output GEMM: d_out[2048,512] f32 = ATT bf16 @ WOb^T + bo ----------
__global__ __launch_bounds__(256) void outg_k(const u16* __restrict__ A,
                                              const u16* __restrict__ Bm,
                                              const float* __restrict__ bias,
                                              float* __restrict__ outF) {
    __shared__ u16 As[64 * 32];
    __shared__ u16 Bs[64 * 32];

    const int t = threadIdx.x;
    const int wave = t >> 6, lane = t & 63;
    const int wr = wave >> 1, wc = wave & 1;
    const int m0 = blockIdx.y * 64, n0 = blockIdx.x * 64;

    f32x4 acc[2][2] = {};
    const int srow = t >> 2, scol = (t & 3) * 8;

    for (int k0 = 0; k0 < 512; k0 += 32) {
        gload_lds16(&A[(size_t)(m0 + srow) * 512 + k0 + scol], &As[t * 8]);
        gload_lds16(&Bm[(size_t)(n0 + srow) * 512 + k0 + scol], &Bs[t * 8]);
        __syncthreads();
        short8 af[2], bfr[2];
#pragma unroll
        for (int i = 0; i < 2; i++)
            af[i] = *(const short8*)&As[(wr * 32 + i * 16 + (lane & 15)) * 32 + ((lane >> 4) << 3)];
#pragma unroll
        for (int jj = 0; jj < 2; jj++)
            bfr[jj] = *(const short8*)&Bs[(wc * 32 + jj * 16 + (lane & 15)) * 32 + ((lane >> 4) << 3)];
#pragma unroll
        for (int i = 0; i < 2; i++)
#pragma unroll
            for (int jj = 0; jj < 2; jj++)
                acc[i][jj] = __builtin_amdgcn_mfma_f32_16x16x32_bf16(af[i], bfr[jj], acc[i][jj], 0, 0, 0);
        __syncthreads();
    }

#pragma unroll
    for (int i = 0; i < 2; i++)
#pragma unroll
        for (int jj = 0; jj < 2; jj++)
#pragma unroll
            for (int r = 0; r < 4; r++) {
                int row = m0 + wr * 32 + i * 16 + ((lane >> 4) << 2) + r;
                int col = n0 + wc * 32 + jj * 16 + (lane & 15);
                outF[((size_t)row << 9) + col] = acc[i][jj][r] + bias[col];
            }
}

// ---------- launch ----------
extern "C" void kernel_launch(void* const* d_in, const int* in_sizes, int n_in,
                              void* d_out, int out_size, void* d_ws, size_t ws_size,
                              hipStream_t stream) {
    const float* inq = (const float*)d_in[0];
    const float* ink = (const float*)d_in[1];
    const float* inv = (const float*)d_in[2];
    const float* box = (const float*)d_in[3];
    const float* Wq  = (const float*)d_in[4];
    const float* bq  = (const float*)d_in[5];
    const float* Wk  = (const float*)d_in[6];
    const float* bk  = (const float*)d_in[7];
    const float* Wv  = (const float*)d_in[8];
    const float* bv  = (const float*)d_in[9];
    const float* Wo  = (const float*)d_in[10];
    const float* bo  = (const float*)d_in[11];
    const float* WG  = (const float*)d_in[12];
    const float* bG  = (const float*)d_in[13];

    u16* base = (u16*)d_ws;
    u16* Xall = base;                    // XQ,XK,XV bf16 (3 x 1,048,576)
    u16* Wall = base + 3145728;          // WQb,WKb,WVb,WOb bf16 (4 x 262,144)
    u16* Qb   = base + 4194304;          // [B,H,N,64] bf16
    u16* Kb   = base + 5242880;          // [B,H,N,64] bf16
    u16* VT   = base + 6291456;          // [B,H,64,N] bf16
    u16* ATT  = base + 7340032;          // [B,N,512] bf16
    u16* Wp   = base + 8388608;          // [B,H,N,N] f16 geometry weights
    u32* TBw  = (u32*)(base + 16777216); // [8][2048] half2(sin,cos) of w-angles
    u32* TBh  = TBw + 16384;             // [8][2048] half2(sin,cos) of h-angles

    table_k<<<dim3(8), 256, 0, stream>>>(box, TBw, TBh);
    prep_k<<<dim3(1024, 1, 11), 256, 0, stream>>>(inq, ink, inv, Wq, Wk, Wv, Wo,
                                                  box, WG, bG, TBw, TBh,
                                                  Xall, Wall, Wp);

    proj_k<<<dim3(8, 32, 3), 256, 0, stream>>>(Xall, Wall, bq, bk, bv, Qb, Kb, VT);

    attn_k<<<dim3(1024), 256, 0, stream>>>(Qb, Kb, VT, Wp, ATT);

    outg_k<<<dim3(8, 32, 1), 256, 0, stream>>>(ATT, Wall + 786432, bo, (float*)d_out);
}

// Round 11
// 70.412 us; speedup vs baseline: 6.1257x; 1.0952x over previous
//
#include <hip/hip_runtime.h>
#include <hip/hip_bf16.h>
#include <cstdint>

typedef unsigned short u16;
typedef unsigned int u32;
typedef __attribute__((ext_vector_type(8))) short short8;   // 8 bf16 MFMA A/B frag
typedef __attribute__((ext_vector_type(4))) float f32x4;    // MFMA C/D frag
typedef __attribute__((ext_vector_type(4))) unsigned int u32x4;
typedef __attribute__((ext_vector_type(4))) unsigned short u16x4;

#define REV 15.91549431f   // 100/(2*pi): the "100*pos" angle in revolutions

// ---------- helpers ----------
__device__ __forceinline__ u16 f2b(float x) { return __builtin_bit_cast(u16, (__bf16)x); }
__device__ __forceinline__ u16 f2h(float x) { return __builtin_bit_cast(u16, (_Float16)x); }
__device__ __forceinline__ float c_dim_f(int f) {
    const float c[8] = {1.0f, 0.42169650f, 0.17782794f, 0.074989421f,
                        0.031622777f, 0.013335214f, 0.0056234132f, 0.0023713737f};
    return c[f];
}
__device__ __forceinline__ void gload_lds16(const void* g, void* l) {
    __builtin_amdgcn_global_load_lds((const __attribute__((address_space(1))) u32*)g,
                                     (__attribute__((address_space(3))) u32*)l, 16, 0, 0);
}

// ---------- prep: f32->bf16 cvt (z 0..6) + geometry weights (z 7..10) ----------
// z 0..2: X inputs -> Xall;  z 3..6: weights -> Wall [x<256]
// z 7..10: geom for b=z-7: w = 1024*max(relu(emb@WG+bG),1e-6) stored f16
// (consumed multiplicatively: softmax(log(w)+s) == normalized w*e^s).
__global__ __launch_bounds__(256) void prep_k(const float* __restrict__ s0,
                                              const float* __restrict__ s1,
                                              const float* __restrict__ s2,
                                              const float* __restrict__ s3,
                                              const float* __restrict__ s4,
                                              const float* __restrict__ s5,
                                              const float* __restrict__ s6,
                                              const float* __restrict__ box,
                                              const float* __restrict__ WG,
                                              const float* __restrict__ bG,
                                              u16* __restrict__ dstX,
                                              u16* __restrict__ dstW,
                                              u16* __restrict__ outW) {
    __shared__ char embs[256 * 128];   // [256 pairs][64 bf16] rows, 128B each
    const int z = blockIdx.z;
    const int t = threadIdx.x;

    if (z < 7) {
        const float* s;
        u16* dst;
        if (z < 3) {
            s = (z == 0) ? s0 : (z == 1) ? s1 : s2;
            dst = dstX + (size_t)z * 1048576;
        } else {
            if (blockIdx.x >= 256) return;
            s = (z == 3) ? s3 : (z == 4) ? s4 : (z == 5) ? s5 : s6;
            dst = dstW + (size_t)(z - 3) * 262144;
        }
        int i = (blockIdx.x * 256 + t) * 4;
        float4 v = *(const float4*)&s[i];
        u16x4 o = { f2b(v.x), f2b(v.y), f2b(v.z), f2b(v.w) };
        *(u16x4*)&dst[i] = o;
        return;
    }

    // ---------------- geometry ----------------
    const int wave = t >> 6, lane = t & 63;
    const int b = z - 7;
    const int jt = blockIdx.x & 1, ii = blockIdx.x >> 1;
    const int j = (jt << 8) + t;
    const int swz = (t & 7) << 4;

    float4 bi = *(const float4*)&box[(size_t)(((b << 9) + ii) << 2)];
    float4 bj = *(const float4*)&box[(size_t)(((b << 9) + j) << 2)];
    float cxi = (bi.x + bi.z) * 0.5f, cyi = (bi.y + bi.w) * 0.5f;
    float wdi = bi.z - bi.x + 1.0f,   hgi = bi.w - bi.y + 1.0f;
    float cxj = (bj.x + bj.z) * 0.5f, cyj = (bj.y + bj.w) * 0.5f;
    float wdj = bj.z - bj.x + 1.0f,   hgj = bj.w - bj.y + 1.0f;

    float pos[4];
    pos[0] = __logf(fmaxf(fabsf((cxi - cxj) / wdi), 1e-3f));
    pos[1] = __logf(fmaxf(fabsf((cyi - cyj) / hgi), 1e-3f));
    pos[2] = __logf(wdi) - __logf(wdj);
    pos[3] = __logf(hgi) - __logf(hgj);

#pragma unroll
    for (int p = 0; p < 4; p++) {
        float rev = pos[p] * REV;
        u32x4 sp, cp;
#pragma unroll
        for (int f = 0; f < 4; f++) {
            float a0 = rev * c_dim_f(2 * f), a1 = rev * c_dim_f(2 * f + 1);
            sp[f] = (u32)f2b(__builtin_amdgcn_sinf(a0)) | ((u32)f2b(__builtin_amdgcn_sinf(a1)) << 16);
            cp[f] = (u32)f2b(__builtin_amdgcn_cosf(a0)) | ((u32)f2b(__builtin_amdgcn_cosf(a1)) << 16);
        }
        *(u32x4*)(embs + (((t << 7) + (p << 4)) ^ swz)) = sp;
        *(u32x4*)(embs + (((t << 7) + 64 + (p << 4)) ^ swz)) = cp;
    }

    const int hh = lane & 15;
    const int ko = (lane >> 4) << 3;
    short8 bf0 = {0,0,0,0,0,0,0,0}, bf1 = {0,0,0,0,0,0,0,0};
    float bGh = 0.0f;
    if (hh < 8) {
        const float* wrow = WG + hh * 64;
#pragma unroll
        for (int e = 0; e < 8; e++) {
            bf0[e] = (short)f2b(wrow[ko + e]);
            bf1[e] = (short)f2b(wrow[32 + ko + e]);
        }
        bGh = bG[hh];
    }
    __syncthreads();

#pragma unroll
    for (int tt = 0; tt < 4; tt++) {
        int mt = (wave << 2) + tt;
        int row = (mt << 4) + hh;
        int rswz = (row & 7) << 4;
        short8 a0v = *(const short8*)(embs + (((row << 7) + (ko << 1)) ^ rswz));
        short8 a1v = *(const short8*)(embs + (((row << 7) + 64 + (ko << 1)) ^ rswz));
        f32x4 acc = {0.f, 0.f, 0.f, 0.f};
        acc = __builtin_amdgcn_mfma_f32_16x16x32_bf16(a0v, bf0, acc, 0, 0, 0);
        acc = __builtin_amdgcn_mfma_f32_16x16x32_bf16(a1v, bf1, acc, 0, 0, 0);
        if (hh < 8) {
            int j0 = (jt << 8) + (mt << 4) + ((lane >> 4) << 2);
            u16x4 ow;
#pragma unroll
            for (int r = 0; r < 4; r++)
                ow[r] = f2h(fmaxf(acc[r] + bGh, 1e-6f) * 1024.0f);
            *(u16x4*)&outW[((size_t)((b << 3) + hh) << 18) + ((size_t)ii << 9) + j0] = ow;
        }
    }
}

// ---------- fused flash attention: p = w * e^(0.125*QK^T - m), O = PV/l ----------
__global__ __launch_bounds__(256) void attn_k(const u16* __restrict__ Qb,
                                              const u16* __restrict__ Kb,
                                              const u16* __restrict__ VT,
                                              const u16* __restrict__ Wp,
                                              u16* __restrict__ ATT) {
    __shared__ u16 Pl[4][16 * 68];
    __shared__ float Mrg[3][64][25];
    const int t = threadIdx.x;
    const int wave = t >> 6, lane = t & 63;
    const int c = lane & 15, g = lane >> 4;
    const int bid = blockIdx.x;
    const int qb = bid & 31, bh = bid >> 5;
    const int b = bh >> 3, h = bh & 7;
    const int q0 = qb << 4;

    const u16* Qp = Qb + ((size_t)bh << 15);
    const u16* Kp = Kb + ((size_t)bh << 15);
    const u16* Vp = VT + ((size_t)bh << 15);
    const _Float16* Bp = (const _Float16*)Wp + ((size_t)bh << 18) + ((size_t)q0 << 9);

    short8 qf[2];
#pragma unroll
    for (int ks = 0; ks < 2; ks++)
        qf[ks] = *(const short8*)&Qp[(size_t)(q0 + c) * 64 + ks * 32 + g * 8];

    f32x4 o[4] = {};
    float m[4] = {-1e30f, -1e30f, -1e30f, -1e30f};
    float l[4] = {0.f, 0.f, 0.f, 0.f};

    for (int kt = 0; kt < 2; kt++) {
        const int k0 = ((wave << 1) + kt) << 6;
        short8 kf[4][2], vf[4][2];
#pragma unroll
        for (int jj = 0; jj < 4; jj++)
#pragma unroll
            for (int ks = 0; ks < 2; ks++) {
                kf[jj][ks] = *(const short8*)&Kp[(size_t)(k0 + jj * 16 + c) * 64 + ks * 32 + g * 8];
                vf[jj][ks] = *(const short8*)&Vp[(size_t)(jj * 16 + c) * 512 + k0 + ks * 32 + g * 8];
            }
        float wgt[4][4];
#pragma unroll
        for (int jj = 0; jj < 4; jj++)
#pragma unroll
            for (int r = 0; r < 4; r++)
                wgt[jj][r] = (float)Bp[(size_t)(g * 4 + r) * 512 + k0 + jj * 16 + c];

        f32x4 sa[4] = {};
        __builtin_amdgcn_s_setprio(1);
#pragma unroll
        for (int jj = 0; jj < 4; jj++)
#pragma unroll
            for (int ks = 0; ks < 2; ks++)
                sa[jj] = __builtin_amdgcn_mfma_f32_16x16x32_bf16(qf[ks], kf[jj][ks], sa[jj], 0, 0, 0);
        __builtin_amdgcn_s_setprio(0);

        float s[4][4];
#pragma unroll
        for (int r = 0; r < 4; r++) {
#pragma unroll
            for (int jj = 0; jj < 4; jj++)
                s[jj][r] = sa[jj][r] * 0.125f;
            float v = fmaxf(fmaxf(s[0][r], s[1][r]), fmaxf(s[2][r], s[3][r]));
#pragma unroll
            for (int off = 1; off < 16; off <<= 1)
                v = fmaxf(v, __shfl_xor(v, off));
            float mn = fmaxf(m[r], v);
            float alpha = __expf(m[r] - mn);
            m[r] = mn;
            float rs = 0.f;
#pragma unroll
            for (int jj = 0; jj < 4; jj++) {
                float p = wgt[jj][r] * __expf(s[jj][r] - mn);
                s[jj][r] = p;
                rs += p;
            }
#pragma unroll
            for (int off = 1; off < 16; off <<= 1)
                rs += __shfl_xor(rs, off);
            l[r] = l[r] * alpha + rs;
#pragma unroll
            for (int jjo = 0; jjo < 4; jjo++)
                o[jjo][r] *= alpha;
        }

#pragma unroll
        for (int jj = 0; jj < 4; jj++)
#pragma unroll
            for (int r = 0; r < 4; r++)
                Pl[wave][(g * 4 + r) * 68 + jj * 16 + c] = f2b(s[jj][r]);
        asm volatile("s_waitcnt lgkmcnt(0)" ::: "memory");
        __builtin_amdgcn_sched_barrier(0);

        short8 pa[2];
#pragma unroll
        for (int ks = 0; ks < 2; ks++)
            pa[ks] = *(const short8*)&Pl[wave][c * 68 + ks * 32 + g * 8];
        __builtin_amdgcn_s_setprio(1);
#pragma unroll
        for (int jjo = 0; jjo < 4; jjo++)
#pragma unroll
            for (int ks = 0; ks < 2; ks++)
                o[jjo] = __builtin_amdgcn_mfma_f32_16x16x32_bf16(pa[ks], vf[jjo][ks], o[jjo], 0, 0, 0);
        __builtin_amdgcn_s_setprio(0);
        __builtin_amdgcn_sched_barrier(0);
    }

    if (wave > 0) {
#pragma unroll
        for (int r = 0; r < 4; r++) {
            Mrg[wave - 1][lane][r] = m[r];
            Mrg[wave - 1][lane][4 + r] = l[r];
#pragma unroll
            for (int jjo = 0; jjo < 4; jjo++)
                Mrg[wave - 1][lane][8 + jjo * 4 + r] = o[jjo][r];
        }
    }
    __syncthreads();
    if (wave == 0) {
#pragma unroll
        for (int w = 0; w < 3; w++) {
#pragma unroll
            for (int r = 0; r < 4; r++) {
                float m1 = Mrg[w][lane][r];
                float l1 = Mrg[w][lane][4 + r];
                float mn = fmaxf(m[r], m1);
                float a0 = __expf(m[r] - mn), a1 = __expf(m1 - mn);
                m[r] = mn;
                l[r] = l[r] * a0 + l1 * a1;
#pragma unroll
                for (int jjo = 0; jjo < 4; jjo++)
                    o[jjo][r] = o[jjo][r] * a0 + Mrg[w][lane][8 + jjo * 4 + r] * a1;
            }
        }
#pragma unroll
        for (int r = 0; r < 4; r++) {
            float inv = 1.0f / l[r];
            int row = q0 + g * 4 + r;
#pragma unroll
            for (int jjo = 0; jjo < 4; jjo++)
                ATT[(size_t)(((b << 9) + row) << 9) + (h << 6) + jjo * 16 + c] = f2b(o[jjo][r] * inv);
        }
    }
}

// ---------- merged projection GEMM (bf16, global_load_lds staging) ----------
// LDS tiles XOR-swizzled (rule #21): linear gload_lds dest + inverse-swizzled
// GLOBAL column (scol) + swizzled READ — spreads the former 8-way ds_read_b128
// bank conflict (lanes c even -> same 4 banks) down to free 2-way.
__global__ __launch_bounds__(256) void proj_k(const u16* __restrict__ Xall,
                                              const u16* __restrict__ Wall,
                                              const float* __restrict__ bq,
                                              const float* __restrict__ bk,
                                              const float* __restrict__ bv,
                                              u16* __restrict__ Qb,
                                              u16* __restrict__ Kb,
                                              u16* __restrict__ VT) {
    __shared__ u16 As[64 * 32];
    __shared__ u16 Bs[64 * 32];

    const int t = threadIdx.x;
    const int wave = t >> 6, lane = t & 63;
    const int wr = wave >> 1, wc = wave & 1;
    const int m0 = blockIdx.y * 64, n0 = blockIdx.x * 64;
    const int z = blockIdx.z;

    const u16* A  = Xall + (size_t)z * 1048576;
    const u16* Bm = Wall + (size_t)z * 262144;
    const float* bias = (z == 0) ? bq : (z == 1) ? bk : bv;
    u16* out = (z == 0) ? Qb : (z == 1) ? Kb : VT;

    f32x4 acc[2][2] = {};
    const int srow = t >> 2;
    const int scol = (((t & 3) ^ ((t >> 3) & 3)) << 3);   // inverse-swizzled source col
    const int c = lane & 15, g = lane >> 4;
    const int gsw = (g ^ ((c >> 1) & 3)) << 3;            // swizzled read col-group

    for (int k0 = 0; k0 < 512; k0 += 32) {
        gload_lds16(&A[(size_t)(m0 + srow) * 512 + k0 + scol], &As[t * 8]);
        gload_lds16(&Bm[(size_t)(n0 + srow) * 512 + k0 + scol], &Bs[t * 8]);
        __syncthreads();
        short8 af[2], bfr[2];
#pragma unroll
        for (int i = 0; i < 2; i++)
            af[i] = *(const short8*)&As[(wr * 32 + i * 16 + c) * 32 + gsw];
#pragma unroll
        for (int jj = 0; jj < 2; jj++)
            bfr[jj] = *(const short8*)&Bs[(wc * 32 + jj * 16 + c) * 32 + gsw];
#pragma unroll
        for (int i = 0; i < 2; i++)
#pragma unroll
            for (int jj = 0; jj < 2; jj++)
                acc[i][jj] = __builtin_amdgcn_mfma_f32_16x16x32_bf16(af[i], bfr[jj], acc[i][jj], 0, 0, 0);
        __syncthreads();
    }

#pragma unroll
    for (int i = 0; i < 2; i++)
#pragma unroll
        for (int jj = 0; jj < 2; jj++)
#pragma unroll
            for (int r = 0; r < 4; r++) {
                int row = m0 + wr * 32 + i * 16 + ((lane >> 4) << 2) + r;
                int col = n0 + wc * 32 + jj * 16 + (lane & 15);
                float v = acc[i][jj][r] + bias[col];
                int b = row >> 9, rr = row & 511, h = col >> 6, d = col & 63;
                if (z < 2)
                    out[(size_t)((((b << 3) + h) << 9) + rr) * 64 + d] = f2b(v);
                else
                    out[(size_t)((((b << 3) + h) << 6) + d) * 512 + rr] = f2b(v);
            }
}

// ---------- output GEMM: d_out[2048,512] f32 = ATT bf16 @ WOb^T + bo ----------
__global__ __launch_bounds__(256) void outg_k(const u16* __restrict__ A,
                                              const u16* __restrict__ Bm,
                                              const float* __restrict__ bias,
                                              float* __restrict__ outF) {
    __shared__ u16 As[64 * 32];
    __shared__ u16 Bs[64 * 32];

    const int t = threadIdx.x;
    const int wave = t >> 6, lane = t & 63;
    const int wr = wave >> 1, wc = wave & 1;
    const int m0 = blockIdx.y * 64, n0 = blockIdx.x * 64;

    f32x4 acc[2][2] = {};
    const int srow = t >> 2;
    const int scol = (((t & 3) ^ ((t >> 3) & 3)) << 3);
    const int c = lane & 15, g = lane >> 4;
    const int gsw = (g ^ ((c >> 1) & 3)) << 3;

    for (int k0 = 0; k0 < 512; k0 += 32) {
        gload_lds16(&A[(size_t)(m0 + srow) * 512 + k0 + scol], &As[t * 8]);
        gload_lds16(&Bm[(size_t)(n0 + srow) * 512 + k0 + scol], &Bs[t * 8]);
        __syncthreads();
        short8 af[2], bfr[2];
#pragma unroll
        for (int i = 0; i < 2; i++)
            af[i] = *(const short8*)&As[(wr * 32 + i * 16 + c) * 32 + gsw];
#pragma unroll
        for (int jj = 0; jj < 2; jj++)
            bfr[jj] = *(const short8*)&Bs[(wc * 32 + jj * 16 + c) * 32 + gsw];
#pragma unroll
        for (int i = 0; i < 2; i++)
#pragma unroll
            for (int jj = 0; jj < 2; jj++)
                acc[i][jj] = __builtin_amdgcn_mfma_f32_16x16x32_bf16(af[i], bfr[jj], acc[i][jj], 0, 0, 0);
        __syncthreads();
    }

#pragma unroll
    for (int i = 0; i < 2; i++)
#pragma unroll
        for (int jj = 0; jj < 2; jj++)
#pragma unroll
            for (int r = 0; r < 4; r++) {
                int row = m0 + wr * 32 + i * 16 + ((lane >> 4) << 2) + r;
                int col = n0 + wc * 32 + jj * 16 + (lane & 15);
                outF[((size_t)row << 9) + col] = acc[i][jj][r] + bias[col];
            }
}

// ---------- launch ----------
extern "C" void kernel_launch(void* const* d_in, const int* in_sizes, int n_in,
                              void* d_out, int out_size, void* d_ws, size_t ws_size,
                              hipStream_t stream) {
    const float* inq = (const float*)d_in[0];
    const float* ink = (const float*)d_in[1];
    const float* inv = (const float*)d_in[2];
    const float* box = (const float*)d_in[3];
    const float* Wq  = (const float*)d_in[4];
    const float* bq  = (const float*)d_in[5];
    const float* Wk  = (const float*)d_in[6];
    const float* bk  = (const float*)d_in[7];
    const float* Wv  = (const float*)d_in[8];
    const float* bv  = (const float*)d_in[9];
    const float* Wo  = (const float*)d_in[10];
    const float* bo  = (const float*)d_in[11];
    const float* WG  = (const float*)d_in[12];
    const float* bG  = (const float*)d_in[13];

    u16* base = (u16*)d_ws;
    u16* Xall = base;                    // XQ,XK,XV bf16 (3 x 1,048,576)
    u16* Wall = base + 3145728;          // WQb,WKb,WVb,WOb bf16 (4 x 262,144)
    u16* Qb   = base + 4194304;          // [B,H,N,64] bf16
    u16* Kb   = base + 5242880;          // [B,H,N,64] bf16
    u16* VT   = base + 6291456;          // [B,H,64,N] bf16
    u16* ATT  = base + 7340032;          // [B,N,512] bf16
    u16* Wp   = base + 8388608;          // [B,H,N,N] f16 geometry weights

    prep_k<<<dim3(1024, 1, 11), 256, 0, stream>>>(inq, ink, inv, Wq, Wk, Wv, Wo,
                                                  box, WG, bG, Xall, Wall, Wp);

    proj_k<<<dim3(8, 32, 3), 256, 0, stream>>>(Xall, Wall, bq, bk, bv, Qb, Kb, VT);

    attn_k<<<dim3(1024), 256, 0, stream>>>(Qb, Kb, VT, Wp, ATT);

    outg_k<<<dim3(8, 32, 1), 256, 0, stream>>>(ATT, Wall + 786432, bo, (float*)d_out);
}

// Round 12
// 70.375 us; speedup vs baseline: 6.1289x; 1.0005x over previous
//
#include <hip/hip_runtime.h>
#include <hip/hip_bf16.h>
#include <cstdint>

typedef unsigned short u16;
typedef unsigned int u32;
typedef __attribute__((ext_vector_type(8))) short short8;   // 8 bf16 MFMA A/B frag
typedef __attribute__((ext_vector_type(4))) float f32x4;    // MFMA C/D frag
typedef __attribute__((ext_vector_type(4))) unsigned int u32x4;
typedef __attribute__((ext_vector_type(4))) unsigned short u16x4;

#define REV 15.91549431f   // 100/(2*pi): the "100*pos" angle in revolutions

// ---------- helpers ----------
__device__ __forceinline__ u16 f2b(float x) { return __builtin_bit_cast(u16, (__bf16)x); }
__device__ __forceinline__ u16 f2h(float x) { return __builtin_bit_cast(u16, (_Float16)x); }
__device__ __forceinline__ float c_dim_f(int f) {
    const float c[8] = {1.0f, 0.42169650f, 0.17782794f, 0.074989421f,
                        0.031622777f, 0.013335214f, 0.0056234132f, 0.0023713737f};
    return c[f];
}
__device__ __forceinline__ void gload_lds16(const void* g, void* l) {
    __builtin_amdgcn_global_load_lds((const __attribute__((address_space(1))) u32*)g,
                                     (__attribute__((address_space(3))) u32*)l, 16, 0, 0);
}

// ---------- prep: f32->bf16 cvt (z 0..6) + geometry weights (z 7..10) ----------
// z 0..2: X inputs -> Xall;  z 3..6: weights -> Wall [x<256]
// z 7..10: geom for b=z-7: w = 1024*max(relu(emb@WG+bG),1e-6) stored f16
// (consumed multiplicatively: softmax(log(w)+s) == normalized w*e^s).
__global__ __launch_bounds__(256) void prep_k(const float* __restrict__ s0,
                                              const float* __restrict__ s1,
                                              const float* __restrict__ s2,
                                              const float* __restrict__ s3,
                                              const float* __restrict__ s4,
                                              const float* __restrict__ s5,
                                              const float* __restrict__ s6,
                                              const float* __restrict__ box,
                                              const float* __restrict__ WG,
                                              const float* __restrict__ bG,
                                              u16* __restrict__ dstX,
                                              u16* __restrict__ dstW,
                                              u16* __restrict__ outW) {
    __shared__ char embs[256 * 128];   // [256 pairs][64 bf16] rows, 128B each
    const int z = blockIdx.z;
    const int t = threadIdx.x;

    if (z < 7) {
        const float* s;
        u16* dst;
        if (z < 3) {
            s = (z == 0) ? s0 : (z == 1) ? s1 : s2;
            dst = dstX + (size_t)z * 1048576;
        } else {
            if (blockIdx.x >= 256) return;
            s = (z == 3) ? s3 : (z == 4) ? s4 : (z == 5) ? s5 : s6;
            dst = dstW + (size_t)(z - 3) * 262144;
        }
        int i = (blockIdx.x * 256 + t) * 4;
        float4 v = *(const float4*)&s[i];
        u16x4 o = { f2b(v.x), f2b(v.y), f2b(v.z), f2b(v.w) };
        *(u16x4*)&dst[i] = o;
        return;
    }

    // ---------------- geometry ----------------
    const int wave = t >> 6, lane = t & 63;
    const int b = z - 7;
    const int jt = blockIdx.x & 1, ii = blockIdx.x >> 1;
    const int j = (jt << 8) + t;
    const int swz = (t & 7) << 4;

    float4 bi = *(const float4*)&box[(size_t)(((b << 9) + ii) << 2)];
    float4 bj = *(const float4*)&box[(size_t)(((b << 9) + j) << 2)];
    float cxi = (bi.x + bi.z) * 0.5f, cyi = (bi.y + bi.w) * 0.5f;
    float wdi = bi.z - bi.x + 1.0f,   hgi = bi.w - bi.y + 1.0f;
    float cxj = (bj.x + bj.z) * 0.5f, cyj = (bj.y + bj.w) * 0.5f;
    float wdj = bj.z - bj.x + 1.0f,   hgj = bj.w - bj.y + 1.0f;

    float pos[4];
    pos[0] = __logf(fmaxf(fabsf((cxi - cxj) / wdi), 1e-3f));
    pos[1] = __logf(fmaxf(fabsf((cyi - cyj) / hgi), 1e-3f));
    pos[2] = __logf(wdi) - __logf(wdj);
    pos[3] = __logf(hgi) - __logf(hgj);

#pragma unroll
    for (int p = 0; p < 4; p++) {
        float rev = pos[p] * REV;
        u32x4 sp, cp;
#pragma unroll
        for (int f = 0; f < 4; f++) {
            float a0 = rev * c_dim_f(2 * f), a1 = rev * c_dim_f(2 * f + 1);
            sp[f] = (u32)f2b(__builtin_amdgcn_sinf(a0)) | ((u32)f2b(__builtin_amdgcn_sinf(a1)) << 16);
            cp[f] = (u32)f2b(__builtin_amdgcn_cosf(a0)) | ((u32)f2b(__builtin_amdgcn_cosf(a1)) << 16);
        }
        *(u32x4*)(embs + (((t << 7) + (p << 4)) ^ swz)) = sp;
        *(u32x4*)(embs + (((t << 7) + 64 + (p << 4)) ^ swz)) = cp;
    }

    const int hh = lane & 15;
    const int ko = (lane >> 4) << 3;
    short8 bf0 = {0,0,0,0,0,0,0,0}, bf1 = {0,0,0,0,0,0,0,0};
    float bGh = 0.0f;
    if (hh < 8) {
        const float* wrow = WG + hh * 64;
#pragma unroll
        for (int e = 0; e < 8; e++) {
            bf0[e] = (short)f2b(wrow[ko + e]);
            bf1[e] = (short)f2b(wrow[32 + ko + e]);
        }
        bGh = bG[hh];
    }
    __syncthreads();

#pragma unroll
    for (int tt = 0; tt < 4; tt++) {
        int mt = (wave << 2) + tt;
        int row = (mt << 4) + hh;
        int rswz = (row & 7) << 4;
        short8 a0v = *(const short8*)(embs + (((row << 7) + (ko << 1)) ^ rswz));
        short8 a1v = *(const short8*)(embs + (((row << 7) + 64 + (ko << 1)) ^ rswz));
        f32x4 acc = {0.f, 0.f, 0.f, 0.f};
        acc = __builtin_amdgcn_mfma_f32_16x16x32_bf16(a0v, bf0, acc, 0, 0, 0);
        acc = __builtin_amdgcn_mfma_f32_16x16x32_bf16(a1v, bf1, acc, 0, 0, 0);
        if (hh < 8) {
            int j0 = (jt << 8) + (mt << 4) + ((lane >> 4) << 2);
            u16x4 ow;
#pragma unroll
            for (int r = 0; r < 4; r++)
                ow[r] = f2h(fmaxf(acc[r] + bGh, 1e-6f) * 1024.0f);
            *(u16x4*)&outW[((size_t)((b << 3) + hh) << 18) + ((size_t)ii << 9) + j0] = ow;
        }
    }
}

// ---------- fused flash attention: p = w * e^(0.125*QK^T - m), O = PV/l ----------
__global__ __launch_bounds__(256) void attn_k(const u16* __restrict__ Qb,
                                              const u16* __restrict__ Kb,
                                              const u16* __restrict__ VT,
                                              const u16* __restrict__ Wp,
                                              u16* __restrict__ ATT) {
    __shared__ u16 Pl[4][16 * 68];
    __shared__ float Mrg[3][64][25];
    const int t = threadIdx.x;
    const int wave = t >> 6, lane = t & 63;
    const int c = lane & 15, g = lane >> 4;
    const int bid = blockIdx.x;
    const int qb = bid & 31, bh = bid >> 5;
    const int b = bh >> 3, h = bh & 7;
    const int q0 = qb << 4;

    const u16* Qp = Qb + ((size_t)bh << 15);
    const u16* Kp = Kb + ((size_t)bh << 15);
    const u16* Vp = VT + ((size_t)bh << 15);
    const _Float16* Bp = (const _Float16*)Wp + ((size_t)bh << 18) + ((size_t)q0 << 9);

    short8 qf[2];
#pragma unroll
    for (int ks = 0; ks < 2; ks++)
        qf[ks] = *(const short8*)&Qp[(size_t)(q0 + c) * 64 + ks * 32 + g * 8];

    f32x4 o[4] = {};
    float m[4] = {-1e30f, -1e30f, -1e30f, -1e30f};
    float l[4] = {0.f, 0.f, 0.f, 0.f};

    for (int kt = 0; kt < 2; kt++) {
        const int k0 = ((wave << 1) + kt) << 6;
        short8 kf[4][2], vf[4][2];
#pragma unroll
        for (int jj = 0; jj < 4; jj++)
#pragma unroll
            for (int ks = 0; ks < 2; ks++) {
                kf[jj][ks] = *(const short8*)&Kp[(size_t)(k0 + jj * 16 + c) * 64 + ks * 32 + g * 8];
                vf[jj][ks] = *(const short8*)&Vp[(size_t)(jj * 16 + c) * 512 + k0 + ks * 32 + g * 8];
            }
        float wgt[4][4];
#pragma unroll
        for (int jj = 0; jj < 4; jj++)
#pragma unroll
            for (int r = 0; r < 4; r++)
                wgt[jj][r] = (float)Bp[(size_t)(g * 4 + r) * 512 + k0 + jj * 16 + c];

        f32x4 sa[4] = {};
        __builtin_amdgcn_s_setprio(1);
#pragma unroll
        for (int jj = 0; jj < 4; jj++)
#pragma unroll
            for (int ks = 0; ks < 2; ks++)
                sa[jj] = __builtin_amdgcn_mfma_f32_16x16x32_bf16(qf[ks], kf[jj][ks], sa[jj], 0, 0, 0);
        __builtin_amdgcn_s_setprio(0);

        float s[4][4];
#pragma unroll
        for (int r = 0; r < 4; r++) {
#pragma unroll
            for (int jj = 0; jj < 4; jj++)
                s[jj][r] = sa[jj][r] * 0.125f;
            float v = fmaxf(fmaxf(s[0][r], s[1][r]), fmaxf(s[2][r], s[3][r]));
#pragma unroll
            for (int off = 1; off < 16; off <<= 1)
                v = fmaxf(v, __shfl_xor(v, off));
            float mn = fmaxf(m[r], v);
            float alpha = __expf(m[r] - mn);
            m[r] = mn;
            float rs = 0.f;
#pragma unroll
            for (int jj = 0; jj < 4; jj++) {
                float p = wgt[jj][r] * __expf(s[jj][r] - mn);
                s[jj][r] = p;
                rs += p;
            }
#pragma unroll
            for (int off = 1; off < 16; off <<= 1)
                rs += __shfl_xor(rs, off);
            l[r] = l[r] * alpha + rs;
#pragma unroll
            for (int jjo = 0; jjo < 4; jjo++)
                o[jjo][r] *= alpha;
        }

#pragma unroll
        for (int jj = 0; jj < 4; jj++)
#pragma unroll
            for (int r = 0; r < 4; r++)
                Pl[wave][(g * 4 + r) * 68 + jj * 16 + c] = f2b(s[jj][r]);
        asm volatile("s_waitcnt lgkmcnt(0)" ::: "memory");
        __builtin_amdgcn_sched_barrier(0);

        short8 pa[2];
#pragma unroll
        for (int ks = 0; ks < 2; ks++)
            pa[ks] = *(const short8*)&Pl[wave][c * 68 + ks * 32 + g * 8];
        __builtin_amdgcn_s_setprio(1);
#pragma unroll
        for (int jjo = 0; jjo < 4; jjo++)
#pragma unroll
            for (int ks = 0; ks < 2; ks++)
                o[jjo] = __builtin_amdgcn_mfma_f32_16x16x32_bf16(pa[ks], vf[jjo][ks], o[jjo], 0, 0, 0);
        __builtin_amdgcn_s_setprio(0);
        __builtin_amdgcn_sched_barrier(0);
    }

    if (wave > 0) {
#pragma unroll
        for (int r = 0; r < 4; r++) {
            Mrg[wave - 1][lane][r] = m[r];
            Mrg[wave - 1][lane][4 + r] = l[r];
#pragma unroll
            for (int jjo = 0; jjo < 4; jjo++)
                Mrg[wave - 1][lane][8 + jjo * 4 + r] = o[jjo][r];
        }
    }
    __syncthreads();
    if (wave == 0) {
#pragma unroll
        for (int w = 0; w < 3; w++) {
#pragma unroll
            for (int r = 0; r < 4; r++) {
                float m1 = Mrg[w][lane][r];
                float l1 = Mrg[w][lane][4 + r];
                float mn = fmaxf(m[r], m1);
                float a0 = __expf(m[r] - mn), a1 = __expf(m1 - mn);
                m[r] = mn;
                l[r] = l[r] * a0 + l1 * a1;
#pragma unroll
                for (int jjo = 0; jjo < 4; jjo++)
                    o[jjo][r] = o[jjo][r] * a0 + Mrg[w][lane][8 + jjo * 4 + r] * a1;
            }
        }
#pragma unroll
        for (int r = 0; r < 4; r++) {
            float inv = 1.0f / l[r];
            int row = q0 + g * 4 + r;
#pragma unroll
            for (int jjo = 0; jjo < 4; jjo++)
                ATT[(size_t)(((b << 9) + row) << 9) + (h << 6) + jjo * 16 + c] = f2b(o[jjo][r] * inv);
        }
    }
}

// ---------- merged projection GEMM: double-buffered counted-vmcnt staging ----------
// T3/T4-lite (m201/m218 pattern): issue next k-step's global_load_lds BEFORE
// computing current; s_waitcnt vmcnt(2) (own oldest loads) + raw s_barrier —
// every wave's wait covers all waves' buffer-k loads; never drain to 0 in-loop.
__global__ __launch_bounds__(256) void proj_k(const u16* __restrict__ Xall,
                                              const u16* __restrict__ Wall,
                                              const float* __restrict__ bq,
                                              const float* __restrict__ bk,
                                              const float* __restrict__ bv,
                                              u16* __restrict__ Qb,
                                              u16* __restrict__ Kb,
                                              u16* __restrict__ VT) {
    __shared__ u16 As[2][64 * 32];
    __shared__ u16 Bs[2][64 * 32];

    const int t = threadIdx.x;
    const int wave = t >> 6, lane = t & 63;
    const int wr = wave >> 1, wc = wave & 1;
    const int m0 = blockIdx.y * 64, n0 = blockIdx.x * 64;
    const int z = blockIdx.z;

    const u16* A  = Xall + (size_t)z * 1048576;
    const u16* Bm = Wall + (size_t)z * 262144;
    const float* bias = (z == 0) ? bq : (z == 1) ? bk : bv;
    u16* out = (z == 0) ? Qb : (z == 1) ? Kb : VT;

    f32x4 acc[2][2] = {};
    const int srow = t >> 2;
    const int scol = (((t & 3) ^ ((t >> 3) & 3)) << 3);   // inverse-swizzled source col
    const int c = lane & 15, g = lane >> 4;
    const int gsw = (g ^ ((c >> 1) & 3)) << 3;            // swizzled read col-group

    const size_t arow = (size_t)(m0 + srow) * 512 + scol;
    const size_t brow = (size_t)(n0 + srow) * 512 + scol;

    gload_lds16(&A[arow], &As[0][t * 8]);
    gload_lds16(&Bm[brow], &Bs[0][t * 8]);

    int cur = 0;
    for (int k0 = 0; k0 < 512; k0 += 32, cur ^= 1) {
        if (k0 + 32 < 512) {
            gload_lds16(&A[arow + k0 + 32], &As[cur ^ 1][t * 8]);
            gload_lds16(&Bm[brow + k0 + 32], &Bs[cur ^ 1][t * 8]);
            asm volatile("s_waitcnt vmcnt(2)" ::: "memory");
        } else {
            asm volatile("s_waitcnt vmcnt(0)" ::: "memory");
        }
        __builtin_amdgcn_s_barrier();
        __builtin_amdgcn_sched_barrier(0);
        short8 af[2], bfr[2];
#pragma unroll
        for (int i = 0; i < 2; i++)
            af[i] = *(const short8*)&As[cur][(wr * 32 + i * 16 + c) * 32 + gsw];
#pragma unroll
        for (int jj = 0; jj < 2; jj++)
            bfr[jj] = *(const short8*)&Bs[cur][(wc * 32 + jj * 16 + c) * 32 + gsw];
#pragma unroll
        for (int i = 0; i < 2; i++)
#pragma unroll
            for (int jj = 0; jj < 2; jj++)
                acc[i][jj] = __builtin_amdgcn_mfma_f32_16x16x32_bf16(af[i], bfr[jj], acc[i][jj], 0, 0, 0);
        __builtin_amdgcn_sched_barrier(0);
        __builtin_amdgcn_s_barrier();     // all waves done reading buf[cur] before it is re-staged
    }

#pragma unroll
    for (int i = 0; i < 2; i++)
#pragma unroll
        for (int jj = 0; jj < 2; jj++)
#pragma unroll
            for (int r = 0; r < 4; r++) {
                int row = m0 + wr * 32 + i * 16 + ((lane >> 4) << 2) + r;
                int col = n0 + wc * 32 + jj * 16 + (lane & 15);
                float v = acc[i][jj][r] + bias[col];
                int b = row >> 9, rr = row & 511, h = col >> 6, d = col & 63;
                if (z < 2)
                    out[(size_t)((((b << 3) + h) << 9) + rr) * 64 + d] = f2b(v);
                else
                    out[(size_t)((((b << 3) + h) << 6) + d) * 512 + rr] = f2b(v);
            }
}

// ---------- output GEMM (same double-buffered staging) ----------
__global__ __launch_bounds__(256) void outg_k(const u16* __restrict__ A,
                                              const u16* __restrict__ Bm,
                                              const float* __restrict__ bias,
                                              float* __restrict__ outF) {
    __shared__ u16 As[2][64 * 32];
    __shared__ u16 Bs[2][64 * 32];

    const int t = threadIdx.x;
    const int wave = t >> 6, lane = t & 63;
    const int wr = wave >> 1, wc = wave & 1;
    const int m0 = blockIdx.y * 64, n0 = blockIdx.x * 64;

    f32x4 acc[2][2] = {};
    const int srow = t >> 2;
    const int scol = (((t & 3) ^ ((t >> 3) & 3)) << 3);
    const int c = lane & 15, g = lane >> 4;
    const int gsw = (g ^ ((c >> 1) & 3)) << 3;

    const size_t arow = (size_t)(m0 + srow) * 512 + scol;
    const size_t brow = (size_t)(n0 + srow) * 512 + scol;

    gload_lds16(&A[arow], &As[0][t * 8]);
    gload_lds16(&Bm[brow], &Bs[0][t * 8]);

    int cur = 0;
    for (int k0 = 0; k0 < 512; k0 += 32, cur ^= 1) {
        if (k0 + 32 < 512) {
            gload_lds16(&A[arow + k0 + 32], &As[cur ^ 1][t * 8]);
            gload_lds16(&Bm[brow + k0 + 32], &Bs[cur ^ 1][t * 8]);
            asm volatile("s_waitcnt vmcnt(2)" ::: "memory");
        } else {
            asm volatile("s_waitcnt vmcnt(0)" ::: "memory");
        }
        __builtin_amdgcn_s_barrier();
        __builtin_amdgcn_sched_barrier(0);
        short8 af[2], bfr[2];
#pragma unroll
        for (int i = 0; i < 2; i++)
            af[i] = *(const short8*)&As[cur][(wr * 32 + i * 16 + c) * 32 + gsw];
#pragma unroll
        for (int jj = 0; jj < 2; jj++)
            bfr[jj] = *(const short8*)&Bs[cur][(wc * 32 + jj * 16 + c) * 32 + gsw];
#pragma unroll
        for (int i = 0; i < 2; i++)
#pragma unroll
            for (int jj = 0; jj < 2; jj++)
                acc[i][jj] = __builtin_amdgcn_mfma_f32_16x16x32_bf16(af[i], bfr[jj], acc[i][jj], 0, 0, 0);
        __builtin_amdgcn_sched_barrier(0);
        __builtin_amdgcn_s_barrier();
    }

#pragma unroll
    for (int i = 0; i < 2; i++)
#pragma unroll
        for (int jj = 0; jj < 2; jj++)
#pragma unroll
            for (int r = 0; r < 4; r++) {
                int row = m0 + wr * 32 + i * 16 + ((lane >> 4) << 2) + r;
                int col = n0 + wc * 32 + jj * 16 + (lane & 15);
                outF[((size_t)row << 9) + col] = acc[i][jj][r] + bias[col];
            }
}

// ---------- launch ----------
extern "C" void kernel_launch(void* const* d_in, const int* in_sizes, int n_in,
                              void* d_out, int out_size, void* d_ws, size_t ws_size,
                              hipStream_t stream) {
    const float* inq = (const float*)d_in[0];
    const float* ink = (const float*)d_in[1];
    const float* inv = (const float*)d_in[2];
    const float* box = (const float*)d_in[3];
    const float* Wq  = (const float*)d_in[4];
    const float* bq  = (const float*)d_in[5];
    const float* Wk  = (const float*)d_in[6];
    const float* bk  = (const float*)d_in[7];
    const float* Wv  = (const float*)d_in[8];
    const float* bv  = (const float*)d_in[9];
    const float* Wo  = (const float*)d_in[10];
    const float* bo  = (const float*)d_in[11];
    const float* WG  = (const float*)d_in[12];
    const float* bG  = (const float*)d_in[13];

    u16* base = (u16*)d_ws;
    u16* Xall = base;                    // XQ,XK,XV bf16 (3 x 1,048,576)
    u16* Wall = base + 3145728;          // WQb,WKb,WVb,WOb bf16 (4 x 262,144)
    u16* Qb   = base + 4194304;          // [B,H,N,64] bf16
    u16* Kb   = base + 5242880;          // [B,H,N,64] bf16
    u16* VT   = base + 6291456;          // [B,H,64,N] bf16
    u16* ATT  = base + 7340032;          // [B,N,512] bf16
    u16* Wp   = base + 8388608;          // [B,H,N,N] f16 geometry weights

    prep_k<<<dim3(1024, 1, 11), 256, 0, stream>>>(inq, ink, inv, Wq, Wk, Wv, Wo,
                                                  box, WG, bG, Xall, Wall, Wp);

    proj_k<<<dim3(8, 32, 3), 256, 0, stream>>>(Xall, Wall, bq, bk, bv, Qb, Kb, VT);

    attn_k<<<dim3(1024), 256, 0, stream>>>(Qb, Kb, VT, Wp, ATT);

    outg_k<<<dim3(8, 32, 1), 256, 0, stream>>>(ATT, Wall + 786432, bo, (float*)d_out);
}